// Round 14
// baseline (932.289 us; speedup 1.0000x reference)
//
#include <hip/hip_runtime.h>

typedef __attribute__((ext_vector_type(8))) short short8;
typedef __attribute__((ext_vector_type(4))) float f32x4;
typedef __attribute__((ext_vector_type(4))) unsigned short u16x4;
typedef unsigned short u16;

#define D_DIM 1024
#define NKT 32  // K / 32

__device__ __forceinline__ u16 f2bf(float f) {
  unsigned u = __builtin_bit_cast(unsigned, f);
  u += 0x7fffu + ((u >> 16) & 1u);
  return (u16)(u >> 16);
}
__device__ __forceinline__ float bf2f(u16 b) {
  return __builtin_bit_cast(float, ((unsigned)b) << 16);
}
__device__ __forceinline__ float gelu_f(float x) {
  float i = 0.7978845608028654f * (x + 0.044715f * x * x * x);
  float ex = __builtin_amdgcn_exp2f(i * 2.885390081777927f);  // e^{2i}
  float th = 1.0f - 2.0f * __builtin_amdgcn_rcpf(ex + 1.0f);
  return 0.5f * x * (1.0f + th);
}
__device__ __forceinline__ f32x4 mfma16(short8 a, short8 b, f32x4 c) {
  return __builtin_amdgcn_mfma_f32_16x16x32_bf16(a, b, c, 0, 0, 0);
}
__device__ __forceinline__ void glds16(const u16* g, const u16* l) {
  __builtin_amdgcn_global_load_lds(
      (const __attribute__((address_space(1))) void*)g,
      (__attribute__((address_space(3))) void*)l, 16, 0, 0);
}

// ---------------- prep kernels ----------------
__global__ __launch_bounds__(256) void prep_w_kernel(
    const float* __restrict__ W, u16* __restrict__ Wth, u16* __restrict__ Wtl) {
  __shared__ float tile[64][65];
  const int t = threadIdx.x;
  const int k0 = blockIdx.x * 64, n0 = blockIdx.y * 64;
  const size_t lbase = (size_t)blockIdx.z * D_DIM * D_DIM;
#pragma unroll
  for (int j = 0; j < 16; ++j) {
    int idx = t + 256 * j;
    int r = idx >> 6, c = idx & 63;
    tile[r][c] = W[lbase + (size_t)(k0 + r) * D_DIM + (n0 + c)];
  }
  __syncthreads();
#pragma unroll
  for (int j = 0; j < 16; ++j) {
    int idx = t + 256 * j;
    int r = idx >> 6, c = idx & 63;
    float f = tile[c][r];
    u16 hb = f2bf(f);
    u16 lb = f2bf(f - bf2f(hb));
    size_t oidx = lbase + (size_t)(n0 + r) * D_DIM + (k0 + c);
    Wth[oidx] = hb;
    Wtl[oidx] = lb;
  }
}

__global__ __launch_bounds__(256) void prep_x_kernel(
    const float* __restrict__ x, u16* __restrict__ xh, u16* __restrict__ xl,
    int* __restrict__ counts, int M) {
  if (blockIdx.x == 0 && threadIdx.x == 0) {
    counts[0] = M;  // exact count, layer 0
    counts[1] = M;  // padded count, layer 0
  }
  size_t i = ((size_t)blockIdx.x * 256 + threadIdx.x) * 4;
  const float4 v = *(const float4*)(x + i);
  const float fv[4] = {v.x, v.y, v.z, v.w};
  u16x4 h4, l4;
#pragma unroll
  for (int c = 0; c < 4; ++c) {
    u16 hb = f2bf(fv[c]);
    h4[c] = hb;
    l4[c] = f2bf(fv[c] - bf2f(hb));
  }
  *(u16x4*)(xh + i) = h4;
  *(u16x4*)(xl + i) = l4;
}

// ---------------- 128x128 gather-GEMM + ACT epilogue ----------------
// LDS buffer (8192 u16 = 16 KB): Ah[128][32] | Bh[128][32] only; lo planes
// (Al, Bl) are read per-lane from global (L2-resident: all 8 bn-blocks of an
// m-tile share one XCD -> re-reads hit that XCD's L2). 32 KB dbuf -> 4
// blocks/CU (vs 2), ds_read count halves: LDS pipe well below MFMA pipe.
// 16B slot s of row r holds k-chunk s ^ ((r>>1)&3) (bank-uniform).
// Block mapping: mt=(bid&7)+8*(bid>>6) -> active front-packed tiles spread
// across XCDs. Early-exit on padded active count.
__global__ __launch_bounds__(256, 4) void gemm_act_kernel(
    const u16* __restrict__ Ahp, const u16* __restrict__ Alp,
    const u16* __restrict__ Bhp, const u16* __restrict__ Blp,
    const float* __restrict__ bias, const float* __restrict__ halt_w,
    u16* __restrict__ Hh, u16* __restrict__ Hl, float* __restrict__ zpart,
    const int* __restrict__ srcmap, const int* __restrict__ npadp, int M,
    int writeLo) {
  extern __shared__ u16 lds[];  // 2 x 8192 u16 = 32 KB
  const int bid = blockIdx.x;   // 1024 blocks
  const int mt = (bid & 7) + 8 * (bid >> 6);
  const int bm0 = mt * 128;
  if (bm0 >= *npadp) return;
  const int bn0 = ((bid >> 3) & 7) * 128;
  const int t = threadIdx.x;
  const int lane = t & 63, wid = t >> 6;
  const int wr = wid >> 1, wc = wid & 1;
  const int g = lane >> 4, r16 = lane & 15;

  // hi-plane staging: wave wid stages rows [32wid, 32wid+32) of Ah and Bh
  const int lrow = lane >> 2;
  const int lchunk = (lane & 3) ^ ((lane >> 3) & 3);
  const int u0 = 2 * wid;
  int ar0 = bm0 + 16 * u0 + lrow, ar1 = ar0 + 16;
  if (srcmap) {
    ar0 = srcmap[ar0];
    ar1 = srcmap[ar1];
  }
  const int br0 = bn0 + 16 * u0 + lrow, br1 = br0 + 16;
  const u16* aSh0 = Ahp + (size_t)ar0 * D_DIM + lchunk * 8;
  const u16* aSh1 = Ahp + (size_t)ar1 * D_DIM + lchunk * 8;
  const u16* bSh0 = Bhp + (size_t)br0 * D_DIM + lchunk * 8;
  const u16* bSh1 = Bhp + (size_t)br1 * D_DIM + lchunk * 8;
  const int dst0 = u0 * 512 + lane * 8, dst1 = dst0 + 512;

  // lo planes: per-lane global fragment pointers (gathered rows for A)
  const u16* alg[4];
  const u16* blg[4];
#pragma unroll
  for (int i = 0; i < 4; ++i) {
    int am = bm0 + wr * 64 + i * 16 + r16;
    if (srcmap) am = srcmap[am];
    alg[i] = Alp + (size_t)am * D_DIM + g * 8;
    blg[i] = Blp + (size_t)(bn0 + wc * 64 + i * 16 + r16) * D_DIM + g * 8;
  }

  // hi fragment LDS read offsets (u16)
  const int fsw = ((g ^ (r16 >> 1)) & 3) * 8;
  int a_rd[4], b_rd[4];
#pragma unroll
  for (int i = 0; i < 4; ++i) {
    a_rd[i] = (wr * 64 + i * 16 + r16) * 32 + fsw;
    b_rd[i] = 4096 + (wc * 64 + i * 16 + r16) * 32 + fsw;
  }

  f32x4 acc[4][4];
#pragma unroll
  for (int i = 0; i < 4; ++i)
#pragma unroll
    for (int j = 0; j < 4; ++j) acc[i][j] = (f32x4)0.0f;

  auto stage = [&](int kt) {
    const int k0 = kt << 5;
    u16* db = lds + (kt & 1) * 8192;
    glds16(aSh0 + k0, db + dst0);
    glds16(aSh1 + k0, db + dst1);
    glds16(bSh0 + k0, db + 4096 + dst0);
    glds16(bSh1 + k0, db + 4096 + dst1);
  };
  stage(0);

#pragma unroll 1
  for (int kt = 0; kt < NKT; ++kt) {
    asm volatile("s_waitcnt vmcnt(0)" ::: "memory");
    __builtin_amdgcn_s_barrier();
    asm volatile("" ::: "memory");
    const u16* Lb = lds + (kt & 1) * 8192;
    const int kw = kt << 5;  // u16 offset into lo planes
    // lo-plane loads FIRST (so counted vmcnt waits for them never include
    // the next-tile glds prefetch issued below)
    short8 bl[4], al[4];
#pragma unroll
    for (int i = 0; i < 4; ++i) bl[i] = *(const short8*)(blg[i] + kw);
#pragma unroll
    for (int i = 0; i < 4; ++i) al[i] = *(const short8*)(alg[i] + kw);
    __builtin_amdgcn_sched_barrier(0);
    if (kt + 1 < NKT) stage(kt + 1);
    short8 ah[4], bh[4];
#pragma unroll
    for (int i = 0; i < 4; ++i) {
      ah[i] = *(const short8*)(Lb + a_rd[i]);
      bh[i] = *(const short8*)(Lb + b_rd[i]);
    }
    __builtin_amdgcn_s_setprio(1);
#pragma unroll
    for (int i = 0; i < 4; ++i)
#pragma unroll
      for (int n = 0; n < 4; ++n) acc[i][n] = mfma16(ah[i], bh[n], acc[i][n]);
    __builtin_amdgcn_s_setprio(0);
    __builtin_amdgcn_s_setprio(1);
#pragma unroll
    for (int i = 0; i < 4; ++i)
#pragma unroll
      for (int n = 0; n < 4; ++n) acc[i][n] = mfma16(ah[i], bl[n], acc[i][n]);
#pragma unroll
    for (int i = 0; i < 4; ++i)
#pragma unroll
      for (int n = 0; n < 4; ++n) acc[i][n] = mfma16(al[i], bh[n], acc[i][n]);
    __builtin_amdgcn_s_setprio(0);
  }

  __syncthreads();  // K-loop retired; LDS free for epilogue reuse

  float bv[4], hwv[4];
#pragma unroll
  for (int ni = 0; ni < 4; ++ni) {
    int col = bn0 + wc * 64 + ni * 16 + r16;
    bv[ni] = bias[col];
    hwv[ni] = halt_w[col];
  }
  float zp[4][4];
#pragma unroll
  for (int mi = 0; mi < 4; ++mi)
#pragma unroll
    for (int j = 0; j < 4; ++j) {
      float zz = 0.0f;
#pragma unroll
      for (int ni = 0; ni < 4; ++ni) {
        float v = gelu_f(acc[mi][ni][j] + bv[ni]);
        acc[mi][ni][j] = v;
        zz += v * hwv[ni];
      }
      zp[mi][j] = zz;
    }
#pragma unroll
  for (int off = 1; off < 16; off <<= 1)
#pragma unroll
    for (int mi = 0; mi < 4; ++mi)
#pragma unroll
      for (int j = 0; j < 4; ++j) zp[mi][j] += __shfl_xor(zp[mi][j], off);
  float* zf = (float*)lds;  // [2][128]
  if (r16 == 0) {
#pragma unroll
    for (int mi = 0; mi < 4; ++mi)
#pragma unroll
      for (int j = 0; j < 4; ++j)
        zf[wc * 128 + wr * 64 + mi * 16 + g * 4 + j] = zp[mi][j];
  }
  __syncthreads();
  if (t < 128) zpart[(size_t)(bn0 >> 7) * M + bm0 + t] = zf[t] + zf[128 + t];
  __syncthreads();

  u16* hp = lds;  // [128][128] u16 = 32 KB
#pragma unroll
  for (int mi = 0; mi < 4; ++mi)
#pragma unroll
    for (int ni = 0; ni < 4; ++ni)
#pragma unroll
      for (int j = 0; j < 4; ++j)
        hp[(wr * 64 + mi * 16 + g * 4 + j) * 128 + wc * 64 + ni * 16 + r16] =
            f2bf(acc[mi][ni][j]);
  __syncthreads();
#pragma unroll
  for (int p = 0; p < 8; ++p) {
    int idx = p * 256 + t;
    int r = idx >> 4, c = idx & 15;
    *(short8*)(Hh + (size_t)(bm0 + r) * D_DIM + bn0 + c * 8) =
        *(const short8*)&hp[r * 128 + c * 8];
  }
  if (writeLo) {
    __syncthreads();
#pragma unroll
    for (int mi = 0; mi < 4; ++mi)
#pragma unroll
      for (int ni = 0; ni < 4; ++ni)
#pragma unroll
        for (int j = 0; j < 4; ++j) {
          float v = acc[mi][ni][j];
          hp[(wr * 64 + mi * 16 + g * 4 + j) * 128 + wc * 64 + ni * 16 + r16] =
              f2bf(v - bf2f(f2bf(v)));
        }
    __syncthreads();
#pragma unroll
    for (int p = 0; p < 8; ++p) {
      int idx = p * 256 + t;
      int r = idx >> 4, c = idx & 15;
      *(short8*)(Hl + (size_t)(bm0 + r) * D_DIM + bn0 + c * 8) =
          *(const short8*)&hp[r * 128 + c * 8];
    }
  }
}

// ---------------- ACT scalar kernels ----------------
__global__ __launch_bounds__(256) void act_weights_kernel(
    const float* __restrict__ zpart, const float* __restrict__ halt_b,
    float* __restrict__ cum, float* __restrict__ rem, float* __restrict__ pond,
    float* __restrict__ wout, float* __restrict__ wfull,
    int* __restrict__ slotmap, int* __restrict__ last_step,
    const int* __restrict__ idx, const int* __restrict__ np, int step,
    int last, int M) {
  int slot = blockIdx.x * 256 + threadIdx.x;
  if (slot >= *np) return;
  int tok = idx ? idx[slot] : slot;
  float z = halt_b[0];
#pragma unroll
  for (int nb = 0; nb < 8; ++nb) z += zpart[(size_t)nb * M + slot];
  float p = 1.0f / (1.0f + expf(-z));
  float c, r, q;
  if (step == 0) {
    c = 0.0f; r = 1.0f; q = 0.0f;
  } else {
    c = cum[tok]; r = rem[tok]; q = pond[tok];
  }
  float weight = last ? r : (((c + p) >= 0.99f) ? r : p);
  q += weight;
  c += weight;
  r = fmaxf(1.0f - c, 0.0f);
  cum[tok] = c;
  rem[tok] = r;
  pond[tok] = q;
  wout[slot] = weight;
  wfull[(size_t)step * M + tok] = weight;
  slotmap[(size_t)step * M + tok] = slot;
  last_step[tok] = step;
}

__global__ __launch_bounds__(1024) void compact_kernel(
    const float* __restrict__ rem, const int* __restrict__ idx_cur,
    const int* __restrict__ ncur_p, int* __restrict__ idx_next,
    int* __restrict__ src_next, int* __restrict__ cnt_next) {
  __shared__ int sc[1024];
  const int t = threadIdx.x;
  const int n = *ncur_p;
  const int base = t * 16;
  int lc = 0;
#pragma unroll
  for (int i = 0; i < 16; ++i) {
    int j = base + i;
    if (j < n) {
      int tok = idx_cur ? idx_cur[j] : j;
      if (rem[tok] > 0.0f) ++lc;
    }
  }
  sc[t] = lc;
  __syncthreads();
  for (int d = 1; d < 1024; d <<= 1) {
    int v = (t >= d) ? sc[t - d] : 0;
    __syncthreads();
    sc[t] += v;
    __syncthreads();
  }
  int pos = sc[t] - lc;
  const int total = sc[1023];
#pragma unroll
  for (int i = 0; i < 16; ++i) {
    int j = base + i;
    if (j < n) {
      int tok = idx_cur ? idx_cur[j] : j;
      if (rem[tok] > 0.0f) {
        idx_next[pos] = tok;
        src_next[pos] = j;
        ++pos;
      }
    }
  }
  if (t == 0) {
    int pad = (total + 127) & ~127;
    cnt_next[0] = total;
    cnt_next[1] = pad;
    for (int j = total; j < pad; ++j) {
      idx_next[j] = -1;
      src_next[j] = 0;
    }
  }
}

// Fallback per-step: out[tok] (+)= w[slot] * h[slot]   (hi plane only)
__global__ __launch_bounds__(256) void act_out_kernel(
    const u16* __restrict__ h, const float* __restrict__ w,
    const int* __restrict__ idx, const int* __restrict__ np, int accum,
    float* __restrict__ out) {
  size_t gid = (size_t)blockIdx.x * 256 + threadIdx.x;
  int slot = (int)(gid >> 7);
  if (slot >= *np) return;
  int off = ((int)gid & 127) * 8;
  int tok = idx ? idx[slot] : slot;
  size_t hb = (size_t)slot * D_DIM + off;
  size_t ob = (size_t)tok * D_DIM + off;
  float ws = w[slot];
  short8 hi = *(const short8*)(h + hb);
  float o[8];
  if (accum) {
    float4 a = *(const float4*)(out + ob);
    float4 b = *(const float4*)(out + ob + 4);
    o[0] = a.x; o[1] = a.y; o[2] = a.z; o[3] = a.w;
    o[4] = b.x; o[5] = b.y; o[6] = b.z; o[7] = b.w;
  } else {
#pragma unroll
    for (int j = 0; j < 8; ++j) o[j] = 0.0f;
  }
#pragma unroll
  for (int j = 0; j < 8; ++j) o[j] += ws * bf2f((u16)hi[j]);
  *(float4*)(out + ob) = make_float4(o[0], o[1], o[2], o[3]);
  *(float4*)(out + ob + 4) = make_float4(o[4], o[5], o[6], o[7]);
}

// Deferred: out[tok] = sum_{s<=ls} wfull[s][tok] * H_{s+1}[slotmap[s][tok]]
__global__ __launch_bounds__(256) void act_out_final_kernel(
    const u16* __restrict__ h1, const u16* __restrict__ h2,
    const u16* __restrict__ h3, const u16* __restrict__ h4,
    const float* __restrict__ wfull, const int* __restrict__ slotmap,
    const int* __restrict__ last_step, float* __restrict__ out, int M) {
  size_t gid = (size_t)blockIdx.x * 256 + threadIdx.x;
  int tok = (int)(gid >> 7);
  int off = ((int)gid & 127) * 8;
  const int ls = last_step[tok];
  float o[8];
#pragma unroll
  for (int j = 0; j < 8; ++j) o[j] = 0.0f;
  for (int s = 0; s <= ls; ++s) {
    int slot = slotmap[(size_t)s * M + tok];
    float w = wfull[(size_t)s * M + tok];
    const u16* b = (s == 0) ? h1 : (s == 1) ? h2 : (s == 2) ? h3 : h4;
    short8 hv = *(const short8*)(b + (size_t)slot * D_DIM + off);
#pragma unroll
    for (int j = 0; j < 8; ++j) o[j] += w * bf2f((u16)hv[j]);
  }
  size_t ob = (size_t)tok * D_DIM + off;
  *(float4*)(out + ob) = make_float4(o[0], o[1], o[2], o[3]);
  *(float4*)(out + ob + 4) = make_float4(o[4], o[5], o[6], o[7]);
}

__global__ __launch_bounds__(256) void ponder_reduce_kernel(
    const float* __restrict__ pond, float* __restrict__ o, int n) {
  __shared__ float sh[256];
  float a = 0.0f;
  for (int i = threadIdx.x; i < n; i += 256) a += pond[i];
  sh[threadIdx.x] = a;
  __syncthreads();
  for (int s = 128; s; s >>= 1) {
    if ((int)threadIdx.x < s) sh[threadIdx.x] += sh[threadIdx.x + s];
    __syncthreads();
  }
  if (threadIdx.x == 0) o[0] = sh[0] / (float)n;
}

extern "C" void kernel_launch(void* const* d_in, const int* in_sizes, int n_in,
                              void* d_out, int out_size, void* d_ws,
                              size_t ws_size, hipStream_t stream) {
  const float* x = (const float*)d_in[0];
  const float* layer_w = (const float*)d_in[1];
  const float* layer_b = (const float*)d_in[2];
  const float* halt_w = (const float*)d_in[3];
  const float* halt_b = (const float*)d_in[4];
  float* out = (float*)d_out;

  const int D = D_DIM;
  const int M = in_sizes[0] / D;        // 16384
  const int L = in_sizes[1] / (D * D);  // 4
  const size_t MD = (size_t)M * D, DD = (size_t)D * D;

  char* ws = (char*)d_ws;
  size_t off = 0;
  auto alloc = [&](size_t bytes) {
    void* p = ws + off;
    off += (bytes + 255) & ~(size_t)255;
    return p;
  };
  u16* Wsplit = (u16*)alloc((size_t)L * 2 * DD * sizeof(u16));  // hi | lo
  float* zpart = (float*)alloc(8 * (size_t)M * 4);
  float* wbuf = (float*)alloc((size_t)M * 4);
  float* wfull = (float*)alloc((size_t)L * M * 4);
  int* slotmap = (int*)alloc((size_t)L * M * 4);
  int* last_step = (int*)alloc((size_t)M * 4);
  float* cum = (float*)alloc((size_t)M * 4);
  float* rem = (float*)alloc((size_t)M * 4);
  float* pond = (float*)alloc((size_t)M * 4);
  int* counts = (int*)alloc(16 * sizeof(int));  // [2s]=exact, [2s+1]=pad
  int* idxA = (int*)alloc((size_t)M * 4);
  int* idxB = (int*)alloc((size_t)M * 4);
  int* srcb = (int*)alloc((size_t)M * 4);

  // planes: x pair always; deferred adds 2 archive hi planes + 2 lo planes
  // (A3/A4 overlay the dead x pair); fallback adds one full pair.
  u16* xpair = (u16*)alloc(2 * MD * sizeof(u16));  // [xh | xl]
  const bool deferred = (off + 2 * (2 * MD * sizeof(u16)) + 4096) <= ws_size;
  u16 *arch = nullptr, *lopp = nullptr, *P1 = nullptr;
  if (deferred) {
    arch = (u16*)alloc(2 * MD * sizeof(u16));  // A1 | A2
    lopp = (u16*)alloc(2 * MD * sizeof(u16));  // LB0 | LB1
  } else {
    P1 = (u16*)alloc(2 * MD * sizeof(u16));
  }
  u16* A[5] = {nullptr, arch, arch ? arch + MD : nullptr, xpair, xpair + MD};

  hipFuncSetAttribute((const void*)gemm_act_kernel,
                      hipFuncAttributeMaxDynamicSharedMemorySize, 32768);

  prep_x_kernel<<<(unsigned)(MD / 1024), 256, 0, stream>>>(x, xpair,
                                                           xpair + MD, counts,
                                                           M);
  prep_w_kernel<<<dim3(D / 64, D / 64, L), 256, 0, stream>>>(
      layer_w, Wsplit, Wsplit + (size_t)L * DD);

  for (int s = 0; s < L; ++s) {
    const int* idxs = (s == 0) ? nullptr : ((s & 1) ? idxB : idxA);
    const u16 *Ahp, *Alp;
    u16 *Hh, *Hl;
    if (deferred) {
      Ahp = (s == 0) ? xpair : A[s];
      Alp = (s == 0) ? (xpair + MD) : (lopp + (size_t)((s - 1) & 1) * MD);
      Hh = A[s + 1];
      Hl = lopp + (size_t)(s & 1) * MD;
    } else {
      u16* pin = (s & 1) ? P1 : xpair;
      u16* pout = (s & 1) ? xpair : P1;
      Ahp = pin;
      Alp = pin + MD;
      Hh = pout;
      Hl = pout + MD;
    }
    gemm_act_kernel<<<dim3((M / 128) * (D / 128)), 256, 32768, stream>>>(
        Ahp, Alp, Wsplit + (size_t)s * DD, Wsplit + (size_t)(L + s) * DD,
        layer_b + (size_t)s * D, halt_w, Hh, Hl, zpart,
        (s == 0) ? nullptr : srcb, counts + 2 * s + 1, M,
        (s < L - 1) ? 1 : 0);
    act_weights_kernel<<<M / 256, 256, 0, stream>>>(
        zpart, halt_b, cum, rem, pond, wbuf, wfull, slotmap, last_step, idxs,
        counts + 2 * s, s, (s == L - 1) ? 1 : 0, M);
    if (!deferred)
      act_out_kernel<<<(unsigned)(MD / 2048), 256, 0, stream>>>(
          Hh, wbuf, idxs, counts + 2 * s, (s > 0) ? 1 : 0, out);
    if (s + 1 < L) {
      int* idxn = ((s + 1) & 1) ? idxB : idxA;
      compact_kernel<<<1, 1024, 0, stream>>>(rem, idxs, counts + 2 * s, idxn,
                                             srcb, counts + 2 * (s + 1));
    }
  }
  if (deferred)
    act_out_final_kernel<<<(unsigned)(MD / 2048), 256, 0, stream>>>(
        A[1], A[2], A[3], A[4], wfull, slotmap, last_step, out, M);
  ponder_reduce_kernel<<<1, 256, 0, stream>>>(pond, out + MD, M);
}

// Round 15
// 683.258 us; speedup vs baseline: 1.3645x; 1.3645x over previous
//
#include <hip/hip_runtime.h>

typedef __attribute__((ext_vector_type(8))) short short8;
typedef __attribute__((ext_vector_type(4))) float f32x4;
typedef __attribute__((ext_vector_type(4))) unsigned short u16x4;
typedef unsigned short u16;

#define D_DIM 1024
#define NKT 32  // K / 32

__device__ __forceinline__ u16 f2bf(float f) {
  unsigned u = __builtin_bit_cast(unsigned, f);
  u += 0x7fffu + ((u >> 16) & 1u);
  return (u16)(u >> 16);
}
__device__ __forceinline__ float bf2f(u16 b) {
  return __builtin_bit_cast(float, ((unsigned)b) << 16);
}
__device__ __forceinline__ float gelu_f(float x) {
  float i = 0.7978845608028654f * (x + 0.044715f * x * x * x);
  float ex = __builtin_amdgcn_exp2f(i * 2.885390081777927f);  // e^{2i}
  float th = 1.0f - 2.0f * __builtin_amdgcn_rcpf(ex + 1.0f);
  return 0.5f * x * (1.0f + th);
}
__device__ __forceinline__ f32x4 mfma16(short8 a, short8 b, f32x4 c) {
  return __builtin_amdgcn_mfma_f32_16x16x32_bf16(a, b, c, 0, 0, 0);
}
__device__ __forceinline__ void glds16(const u16* g, const u16* l) {
  __builtin_amdgcn_global_load_lds(
      (const __attribute__((address_space(1))) void*)g,
      (__attribute__((address_space(3))) void*)l, 16, 0, 0);
}

// ---------------- fused prep: W split+transpose (blocks 0..1023) and
// x hi/lo split (blocks 1024..) ----------------
__global__ __launch_bounds__(256) void prep_kernel(
    const float* __restrict__ W, u16* __restrict__ Wth, u16* __restrict__ Wtl,
    const float* __restrict__ x, u16* __restrict__ xh, u16* __restrict__ xl,
    int* __restrict__ counts, int M) {
  __shared__ float tile[64][65];
  const int bid = blockIdx.x;
  const int t = threadIdx.x;
  if (bid < 1024) {
    const int k0 = (bid & 15) * 64, n0 = ((bid >> 4) & 15) * 64;
    const size_t lbase = (size_t)(bid >> 8) * D_DIM * D_DIM;
#pragma unroll
    for (int j = 0; j < 16; ++j) {
      int idx = t + 256 * j;
      int r = idx >> 6, c = idx & 63;
      tile[r][c] = W[lbase + (size_t)(k0 + r) * D_DIM + (n0 + c)];
    }
    __syncthreads();
#pragma unroll
    for (int j = 0; j < 16; ++j) {
      int idx = t + 256 * j;
      int r = idx >> 6, c = idx & 63;
      float f = tile[c][r];
      u16 hb = f2bf(f);
      u16 lb = f2bf(f - bf2f(hb));
      size_t oidx = lbase + (size_t)(n0 + r) * D_DIM + (k0 + c);
      Wth[oidx] = hb;
      Wtl[oidx] = lb;
    }
  } else {
    if (bid == 1024 && t == 0) {
      counts[0] = M;  // exact count, layer 0
      counts[1] = M;  // padded count, layer 0
    }
    size_t i = ((size_t)(bid - 1024) * 256 + t) * 4;
    const float4 v = *(const float4*)(x + i);
    const float fv[4] = {v.x, v.y, v.z, v.w};
    u16x4 h4, l4;
#pragma unroll
    for (int c = 0; c < 4; ++c) {
      u16 hb = f2bf(fv[c]);
      h4[c] = hb;
      l4[c] = f2bf(fv[c] - bf2f(hb));
    }
    *(u16x4*)(xh + i) = h4;
    *(u16x4*)(xl + i) = l4;
  }
}

// ---------------- 128x128 gather-GEMM + ACT epilogue ----------------
// (identical to round 13: 32 KB dbuf, XOR bank-uniform layout, interleaved
// XCD map mt=(bid&7)+8*(bid>>6), early-exit on padded active count.)
__global__ __launch_bounds__(256, 2) void gemm_act_kernel(
    const u16* __restrict__ Ahp, const u16* __restrict__ Alp,
    const u16* __restrict__ Bhp, const u16* __restrict__ Blp,
    const float* __restrict__ bias, const float* __restrict__ halt_w,
    u16* __restrict__ Hh, u16* __restrict__ Hl, float* __restrict__ zpart,
    const int* __restrict__ srcmap, const int* __restrict__ npadp, int M,
    int writeLo) {
  extern __shared__ u16 lds[];  // 2 x 16384 u16
  const int bid = blockIdx.x;   // 1024 blocks
  const int mt = (bid & 7) + 8 * (bid >> 6);
  const int bm0 = mt * 128;
  if (bm0 >= *npadp) return;
  const int bn0 = ((bid >> 3) & 7) * 128;
  const int t = threadIdx.x;
  const int lane = t & 63, wid = t >> 6;
  const int wr = wid >> 1, wc = wid & 1;
  const int g = lane >> 4, r16 = lane & 15;

  const int lrow = lane >> 2;
  const int lchunk = (lane & 3) ^ ((lane >> 3) & 3);
  const int u0 = 2 * wid;
  int ar0 = bm0 + 16 * u0 + lrow, ar1 = ar0 + 16;
  if (srcmap) {
    ar0 = srcmap[ar0];
    ar1 = srcmap[ar1];
  }
  const int br0 = bn0 + 16 * u0 + lrow, br1 = br0 + 16;
  const u16* aSh0 = Ahp + (size_t)ar0 * D_DIM + lchunk * 8;
  const u16* aSh1 = Ahp + (size_t)ar1 * D_DIM + lchunk * 8;
  const u16* aSl0 = Alp + (size_t)ar0 * D_DIM + lchunk * 8;
  const u16* aSl1 = Alp + (size_t)ar1 * D_DIM + lchunk * 8;
  const u16* bSh0 = Bhp + (size_t)br0 * D_DIM + lchunk * 8;
  const u16* bSh1 = Bhp + (size_t)br1 * D_DIM + lchunk * 8;
  const u16* bSl0 = Blp + (size_t)br0 * D_DIM + lchunk * 8;
  const u16* bSl1 = Blp + (size_t)br1 * D_DIM + lchunk * 8;
  const int dst0 = u0 * 512 + lane * 8, dst1 = dst0 + 512;

  const int fsw = ((g ^ (r16 >> 1)) & 3) * 8;
  int a_rd[4], b_rd[4];
#pragma unroll
  for (int i = 0; i < 4; ++i) {
    a_rd[i] = (wr * 64 + i * 16 + r16) * 32 + fsw;
    b_rd[i] = 8192 + (wc * 64 + i * 16 + r16) * 32 + fsw;
  }

  f32x4 acc[4][4];
#pragma unroll
  for (int i = 0; i < 4; ++i)
#pragma unroll
    for (int j = 0; j < 4; ++j) acc[i][j] = (f32x4)0.0f;

  auto stage = [&](int kt) {
    const int k0 = kt << 5;
    u16* db = lds + (kt & 1) * 16384;
    glds16(aSh0 + k0, db + dst0);
    glds16(aSh1 + k0, db + dst1);
    glds16(aSl0 + k0, db + 4096 + dst0);
    glds16(aSl1 + k0, db + 4096 + dst1);
    glds16(bSh0 + k0, db + 8192 + dst0);
    glds16(bSh1 + k0, db + 8192 + dst1);
    glds16(bSl0 + k0, db + 12288 + dst0);
    glds16(bSl1 + k0, db + 12288 + dst1);
  };
  stage(0);

#pragma unroll 1
  for (int kt = 0; kt < NKT; ++kt) {
    asm volatile("s_waitcnt vmcnt(0)" ::: "memory");
    __builtin_amdgcn_s_barrier();
    asm volatile("" ::: "memory");
    const u16* Lb = lds + (kt & 1) * 16384;
    if (kt + 1 < NKT) stage(kt + 1);
    short8 ah[4], al[4], bh[4], bl[4];
#pragma unroll
    for (int i = 0; i < 4; ++i) {
      ah[i] = *(const short8*)(Lb + a_rd[i]);
      bh[i] = *(const short8*)(Lb + b_rd[i]);
    }
    __builtin_amdgcn_s_setprio(1);
#pragma unroll
    for (int i = 0; i < 4; ++i)
#pragma unroll
      for (int n = 0; n < 4; ++n) acc[i][n] = mfma16(ah[i], bh[n], acc[i][n]);
    __builtin_amdgcn_s_setprio(0);
#pragma unroll
    for (int i = 0; i < 4; ++i) {
      al[i] = *(const short8*)(Lb + 4096 + a_rd[i]);
      bl[i] = *(const short8*)(Lb + 4096 + b_rd[i]);
    }
    __builtin_amdgcn_s_setprio(1);
#pragma unroll
    for (int i = 0; i < 4; ++i)
#pragma unroll
      for (int n = 0; n < 4; ++n) acc[i][n] = mfma16(ah[i], bl[n], acc[i][n]);
#pragma unroll
    for (int i = 0; i < 4; ++i)
#pragma unroll
      for (int n = 0; n < 4; ++n) acc[i][n] = mfma16(al[i], bh[n], acc[i][n]);
    __builtin_amdgcn_s_setprio(0);
  }

  __syncthreads();

  float bv[4], hwv[4];
#pragma unroll
  for (int ni = 0; ni < 4; ++ni) {
    int col = bn0 + wc * 64 + ni * 16 + r16;
    bv[ni] = bias[col];
    hwv[ni] = halt_w[col];
  }
  float zp[4][4];
#pragma unroll
  for (int mi = 0; mi < 4; ++mi)
#pragma unroll
    for (int j = 0; j < 4; ++j) {
      float zz = 0.0f;
#pragma unroll
      for (int ni = 0; ni < 4; ++ni) {
        float v = gelu_f(acc[mi][ni][j] + bv[ni]);
        acc[mi][ni][j] = v;
        zz += v * hwv[ni];
      }
      zp[mi][j] = zz;
    }
#pragma unroll
  for (int off = 1; off < 16; off <<= 1)
#pragma unroll
    for (int mi = 0; mi < 4; ++mi)
#pragma unroll
      for (int j = 0; j < 4; ++j) zp[mi][j] += __shfl_xor(zp[mi][j], off);
  float* zf = (float*)lds;  // [2][128]
  if (r16 == 0) {
#pragma unroll
    for (int mi = 0; mi < 4; ++mi)
#pragma unroll
      for (int j = 0; j < 4; ++j)
        zf[wc * 128 + wr * 64 + mi * 16 + g * 4 + j] = zp[mi][j];
  }
  __syncthreads();
  if (t < 128) zpart[(size_t)(bn0 >> 7) * M + bm0 + t] = zf[t] + zf[128 + t];
  __syncthreads();

  u16* hp = lds;
#pragma unroll
  for (int mi = 0; mi < 4; ++mi)
#pragma unroll
    for (int ni = 0; ni < 4; ++ni)
#pragma unroll
      for (int j = 0; j < 4; ++j)
        hp[(wr * 64 + mi * 16 + g * 4 + j) * 128 + wc * 64 + ni * 16 + r16] =
            f2bf(acc[mi][ni][j]);
  __syncthreads();
#pragma unroll
  for (int p = 0; p < 8; ++p) {
    int idx = p * 256 + t;
    int r = idx >> 4, c = idx & 15;
    *(short8*)(Hh + (size_t)(bm0 + r) * D_DIM + bn0 + c * 8) =
        *(const short8*)&hp[r * 128 + c * 8];
  }
  if (writeLo) {
    __syncthreads();
#pragma unroll
    for (int mi = 0; mi < 4; ++mi)
#pragma unroll
      for (int ni = 0; ni < 4; ++ni)
#pragma unroll
        for (int j = 0; j < 4; ++j) {
          float v = acc[mi][ni][j];
          hp[(wr * 64 + mi * 16 + g * 4 + j) * 128 + wc * 64 + ni * 16 + r16] =
              f2bf(v - bf2f(f2bf(v)));
        }
    __syncthreads();
#pragma unroll
    for (int p = 0; p < 8; ++p) {
      int idx = p * 256 + t;
      int r = idx >> 4, c = idx & 15;
      *(short8*)(Hl + (size_t)(bm0 + r) * D_DIM + bn0 + c * 8) =
          *(const short8*)&hp[r * 128 + c * 8];
    }
  }
}

// ---------------- fused ACT step: state update + ponder accumulation +
// deterministic compaction, one single-block launch per layer ----------------
__global__ __launch_bounds__(1024) void act_step_kernel(
    const float* __restrict__ zpart, const float* __restrict__ halt_b,
    float* __restrict__ cum, float* __restrict__ rem,
    float* __restrict__ wout, float* __restrict__ wfull,
    int* __restrict__ slotmap, int* __restrict__ last_step,
    const int* __restrict__ idx_cur, const int* __restrict__ ncur_p,
    int* __restrict__ idx_next, int* __restrict__ src_next,
    int* __restrict__ cnt_next, float* __restrict__ psum,
    float* __restrict__ pcost, int step, int last, int do_compact, int M) {
  __shared__ int sc[1024];
  __shared__ float sf[1024];
  const int t = threadIdx.x;
  const int n = *ncur_p;  // exact active count this step
  const float hb = halt_b[0];
  const int base = t * 16;
  int toks[16];
  bool act[16];
  float wsum = 0.0f;
  int lc = 0;
#pragma unroll
  for (int i = 0; i < 16; ++i) {
    toks[i] = -1;
    act[i] = false;
    int j = base + i;
    if (j < n) {
      int tok = idx_cur ? idx_cur[j] : j;
      float z = hb;
#pragma unroll
      for (int nb = 0; nb < 8; ++nb) z += zpart[(size_t)nb * M + j];
      float p = 1.0f / (1.0f + expf(-z));
      float c, r;
      if (step == 0) {
        c = 0.0f; r = 1.0f;
      } else {
        c = cum[tok]; r = rem[tok];
      }
      float weight = last ? r : (((c + p) >= 0.99f) ? r : p);
      c += weight;
      r = fmaxf(1.0f - c, 0.0f);
      cum[tok] = c;
      rem[tok] = r;
      wout[j] = weight;
      wfull[(size_t)step * M + tok] = weight;
      slotmap[(size_t)step * M + tok] = j;
      last_step[tok] = step;
      wsum += weight;
      toks[i] = tok;
      if (r > 0.0f) {
        act[i] = true;
        ++lc;
      }
    }
  }
  sc[t] = lc;
  sf[t] = wsum;
  __syncthreads();
  // inclusive scan on sc (Hillis-Steele)
  for (int d = 1; d < 1024; d <<= 1) {
    int v = (t >= d) ? sc[t - d] : 0;
    __syncthreads();
    sc[t] += v;
    __syncthreads();
  }
  // tree reduce on sf
  for (int s = 512; s; s >>= 1) {
    if (t < s) sf[t] += sf[t + s];
    __syncthreads();
  }
  if (do_compact) {
    int pos = sc[t] - lc;
    const int total = sc[1023];
#pragma unroll
    for (int i = 0; i < 16; ++i) {
      if (act[i]) {
        idx_next[pos] = toks[i];
        src_next[pos] = base + i;
        ++pos;
      }
    }
    if (t == 0) {
      int pad = (total + 127) & ~127;
      cnt_next[0] = total;
      cnt_next[1] = pad;
      for (int j = total; j < pad; ++j) {
        idx_next[j] = -1;
        src_next[j] = 0;
      }
    }
  }
  if (t == 0) {
    float acc = (step == 0) ? sf[0] : (psum[0] + sf[0]);
    psum[0] = acc;
    if (last) pcost[0] = acc / (float)M;
  }
}

// Fallback per-step: out[tok] (+)= w[slot] * h[slot]   (hi plane only)
__global__ __launch_bounds__(256) void act_out_kernel(
    const u16* __restrict__ h, const float* __restrict__ w,
    const int* __restrict__ idx, const int* __restrict__ np, int accum,
    float* __restrict__ out) {
  size_t gid = (size_t)blockIdx.x * 256 + threadIdx.x;
  int slot = (int)(gid >> 7);
  if (slot >= *np) return;
  int off = ((int)gid & 127) * 8;
  int tok = idx ? idx[slot] : slot;
  size_t hb = (size_t)slot * D_DIM + off;
  size_t ob = (size_t)tok * D_DIM + off;
  float ws = w[slot];
  short8 hi = *(const short8*)(h + hb);
  float o[8];
  if (accum) {
    float4 a = *(const float4*)(out + ob);
    float4 b = *(const float4*)(out + ob + 4);
    o[0] = a.x; o[1] = a.y; o[2] = a.z; o[3] = a.w;
    o[4] = b.x; o[5] = b.y; o[6] = b.z; o[7] = b.w;
  } else {
#pragma unroll
    for (int j = 0; j < 8; ++j) o[j] = 0.0f;
  }
#pragma unroll
  for (int j = 0; j < 8; ++j) o[j] += ws * bf2f((u16)hi[j]);
  *(float4*)(out + ob) = make_float4(o[0], o[1], o[2], o[3]);
  *(float4*)(out + ob + 4) = make_float4(o[4], o[5], o[6], o[7]);
}

// Deferred: out[tok] = sum_{s<=ls} wfull[s][tok] * H_{s+1}[slotmap[s][tok]]
__global__ __launch_bounds__(256) void act_out_final_kernel(
    const u16* __restrict__ h1, const u16* __restrict__ h2,
    const u16* __restrict__ h3, const u16* __restrict__ h4,
    const float* __restrict__ wfull, const int* __restrict__ slotmap,
    const int* __restrict__ last_step, float* __restrict__ out, int M) {
  size_t gid = (size_t)blockIdx.x * 256 + threadIdx.x;
  int tok = (int)(gid >> 7);
  int off = ((int)gid & 127) * 8;
  const int ls = last_step[tok];
  float o[8];
#pragma unroll
  for (int j = 0; j < 8; ++j) o[j] = 0.0f;
  for (int s = 0; s <= ls; ++s) {
    int slot = slotmap[(size_t)s * M + tok];
    float w = wfull[(size_t)s * M + tok];
    const u16* b = (s == 0) ? h1 : (s == 1) ? h2 : (s == 2) ? h3 : h4;
    short8 hv = *(const short8*)(b + (size_t)slot * D_DIM + off);
#pragma unroll
    for (int j = 0; j < 8; ++j) o[j] += w * bf2f((u16)hv[j]);
  }
  size_t ob = (size_t)tok * D_DIM + off;
  *(float4*)(out + ob) = make_float4(o[0], o[1], o[2], o[3]);
  *(float4*)(out + ob + 4) = make_float4(o[4], o[5], o[6], o[7]);
}

extern "C" void kernel_launch(void* const* d_in, const int* in_sizes, int n_in,
                              void* d_out, int out_size, void* d_ws,
                              size_t ws_size, hipStream_t stream) {
  const float* x = (const float*)d_in[0];
  const float* layer_w = (const float*)d_in[1];
  const float* layer_b = (const float*)d_in[2];
  const float* halt_w = (const float*)d_in[3];
  const float* halt_b = (const float*)d_in[4];
  float* out = (float*)d_out;

  const int D = D_DIM;
  const int M = in_sizes[0] / D;        // 16384
  const int L = in_sizes[1] / (D * D);  // 4
  const size_t MD = (size_t)M * D, DD = (size_t)D * D;

  char* ws = (char*)d_ws;
  size_t off = 0;
  auto alloc = [&](size_t bytes) {
    void* p = ws + off;
    off += (bytes + 255) & ~(size_t)255;
    return p;
  };
  u16* Wsplit = (u16*)alloc((size_t)L * 2 * DD * sizeof(u16));  // hi | lo
  float* zpart = (float*)alloc(8 * (size_t)M * 4);
  float* wbuf = (float*)alloc((size_t)M * 4);
  float* wfull = (float*)alloc((size_t)L * M * 4);
  int* slotmap = (int*)alloc((size_t)L * M * 4);
  int* last_step = (int*)alloc((size_t)M * 4);
  float* cum = (float*)alloc((size_t)M * 4);
  float* rem = (float*)alloc((size_t)M * 4);
  float* psum = (float*)alloc(256);
  int* counts = (int*)alloc(16 * sizeof(int));  // [2s]=exact, [2s+1]=pad
  int* idxA = (int*)alloc((size_t)M * 4);
  int* idxB = (int*)alloc((size_t)M * 4);
  int* srcb = (int*)alloc((size_t)M * 4);

  // planes: x pair always; deferred adds 2 archive hi planes + 2 lo planes
  // (A3/A4 overlay the dead x pair); fallback adds one full pair.
  u16* xpair = (u16*)alloc(2 * MD * sizeof(u16));  // [xh | xl]
  const bool deferred = (off + 2 * (2 * MD * sizeof(u16)) + 4096) <= ws_size;
  u16 *arch = nullptr, *lopp = nullptr, *P1 = nullptr;
  if (deferred) {
    arch = (u16*)alloc(2 * MD * sizeof(u16));  // A1 | A2
    lopp = (u16*)alloc(2 * MD * sizeof(u16));  // LB0 | LB1
  } else {
    P1 = (u16*)alloc(2 * MD * sizeof(u16));
  }
  u16* A[5] = {nullptr, arch, arch ? arch + MD : nullptr, xpair, xpair + MD};

  hipFuncSetAttribute((const void*)gemm_act_kernel,
                      hipFuncAttributeMaxDynamicSharedMemorySize, 65536);

  prep_kernel<<<(unsigned)(1024 + MD / 1024), 256, 0, stream>>>(
      layer_w, Wsplit, Wsplit + (size_t)L * DD, x, xpair, xpair + MD, counts,
      M);

  for (int s = 0; s < L; ++s) {
    const int* idxs = (s == 0) ? nullptr : ((s & 1) ? idxB : idxA);
    int* idxn = ((s + 1) & 1) ? idxB : idxA;
    const u16 *Ahp, *Alp;
    u16 *Hh, *Hl;
    if (deferred) {
      Ahp = (s == 0) ? xpair : A[s];
      Alp = (s == 0) ? (xpair + MD) : (lopp + (size_t)((s - 1) & 1) * MD);
      Hh = A[s + 1];
      Hl = lopp + (size_t)(s & 1) * MD;
    } else {
      u16* pin = (s & 1) ? P1 : xpair;
      u16* pout = (s & 1) ? xpair : P1;
      Ahp = pin;
      Alp = pin + MD;
      Hh = pout;
      Hl = pout + MD;
    }
    gemm_act_kernel<<<dim3((M / 128) * (D / 128)), 256, 65536, stream>>>(
        Ahp, Alp, Wsplit + (size_t)s * DD, Wsplit + (size_t)(L + s) * DD,
        layer_b + (size_t)s * D, halt_w, Hh, Hl, zpart,
        (s == 0) ? nullptr : srcb, counts + 2 * s + 1, M,
        (s < L - 1) ? 1 : 0);
    act_step_kernel<<<1, 1024, 0, stream>>>(
        zpart, halt_b, cum, rem, wbuf, wfull, slotmap, last_step, idxs,
        counts + 2 * s, idxn, srcb, counts + 2 * (s + 1), psum, out + MD, s,
        (s == L - 1) ? 1 : 0, (s + 1 < L) ? 1 : 0, M);
    if (!deferred)
      act_out_kernel<<<(unsigned)(MD / 2048), 256, 0, stream>>>(
          Hh, wbuf, idxs, counts + 2 * s, (s > 0) ? 1 : 0, out);
  }
  if (deferred)
    act_out_final_kernel<<<(unsigned)(MD / 2048), 256, 0, stream>>>(
        A[1], A[2], A[3], A[4], wfull, slotmap, last_step, out, M);
}

// Round 16
// 463.081 us; speedup vs baseline: 2.0132x; 1.4755x over previous
//
#include <hip/hip_runtime.h>

typedef __attribute__((ext_vector_type(8))) short short8;
typedef __attribute__((ext_vector_type(4))) float f32x4;
typedef __attribute__((ext_vector_type(4))) unsigned short u16x4;
typedef unsigned short u16;

#define D_DIM 1024
#define NKT 32  // K / 32

__device__ __forceinline__ u16 f2bf(float f) {
  unsigned u = __builtin_bit_cast(unsigned, f);
  u += 0x7fffu + ((u >> 16) & 1u);
  return (u16)(u >> 16);
}
__device__ __forceinline__ float bf2f(u16 b) {
  return __builtin_bit_cast(float, ((unsigned)b) << 16);
}
__device__ __forceinline__ float gelu_f(float x) {
  float i = 0.7978845608028654f * (x + 0.044715f * x * x * x);
  float ex = __builtin_amdgcn_exp2f(i * 2.885390081777927f);  // e^{2i}
  float th = 1.0f - 2.0f * __builtin_amdgcn_rcpf(ex + 1.0f);
  return 0.5f * x * (1.0f + th);
}
__device__ __forceinline__ f32x4 mfma16(short8 a, short8 b, f32x4 c) {
  return __builtin_amdgcn_mfma_f32_16x16x32_bf16(a, b, c, 0, 0, 0);
}
__device__ __forceinline__ void glds16(const u16* g, const u16* l) {
  __builtin_amdgcn_global_load_lds(
      (const __attribute__((address_space(1))) void*)g,
      (__attribute__((address_space(3))) void*)l, 16, 0, 0);
}

// ---------------- fused prep: W split+transpose (blocks 0..1023) and
// x hi/lo split (blocks 1024..) ----------------
__global__ __launch_bounds__(256) void prep_kernel(
    const float* __restrict__ W, u16* __restrict__ Wth, u16* __restrict__ Wtl,
    const float* __restrict__ x, u16* __restrict__ xh, u16* __restrict__ xl,
    int* __restrict__ counts, int M) {
  __shared__ float tile[64][65];
  const int bid = blockIdx.x;
  const int t = threadIdx.x;
  if (bid < 1024) {
    const int k0 = (bid & 15) * 64, n0 = ((bid >> 4) & 15) * 64;
    const size_t lbase = (size_t)(bid >> 8) * D_DIM * D_DIM;
#pragma unroll
    for (int j = 0; j < 16; ++j) {
      int idx = t + 256 * j;
      int r = idx >> 6, c = idx & 63;
      tile[r][c] = W[lbase + (size_t)(k0 + r) * D_DIM + (n0 + c)];
    }
    __syncthreads();
#pragma unroll
    for (int j = 0; j < 16; ++j) {
      int idx = t + 256 * j;
      int r = idx >> 6, c = idx & 63;
      float f = tile[c][r];
      u16 hb = f2bf(f);
      u16 lb = f2bf(f - bf2f(hb));
      size_t oidx = lbase + (size_t)(n0 + r) * D_DIM + (k0 + c);
      Wth[oidx] = hb;
      Wtl[oidx] = lb;
    }
  } else {
    if (bid == 1024 && t == 0) {
      counts[0] = M;  // exact count, layer 0
      counts[1] = M;  // padded count, layer 0
    }
    size_t i = ((size_t)(bid - 1024) * 256 + t) * 4;
    const float4 v = *(const float4*)(x + i);
    const float fv[4] = {v.x, v.y, v.z, v.w};
    u16x4 h4, l4;
#pragma unroll
    for (int c = 0; c < 4; ++c) {
      u16 hb = f2bf(fv[c]);
      h4[c] = hb;
      l4[c] = f2bf(fv[c] - bf2f(hb));
    }
    *(u16x4*)(xh + i) = h4;
    *(u16x4*)(xl + i) = l4;
  }
}

// ---------------- 128x128 gather-GEMM + ACT epilogue ----------------
// (identical to round 13: 32 KB dbuf, XOR bank-uniform layout, interleaved
// XCD map mt=(bid&7)+8*(bid>>6), early-exit on padded active count.)
__global__ __launch_bounds__(256, 2) void gemm_act_kernel(
    const u16* __restrict__ Ahp, const u16* __restrict__ Alp,
    const u16* __restrict__ Bhp, const u16* __restrict__ Blp,
    const float* __restrict__ bias, const float* __restrict__ halt_w,
    u16* __restrict__ Hh, u16* __restrict__ Hl, float* __restrict__ zpart,
    const int* __restrict__ srcmap, const int* __restrict__ npadp, int M,
    int writeLo) {
  extern __shared__ u16 lds[];  // 2 x 16384 u16
  const int bid = blockIdx.x;   // 1024 blocks
  const int mt = (bid & 7) + 8 * (bid >> 6);
  const int bm0 = mt * 128;
  if (bm0 >= *npadp) return;
  const int bn0 = ((bid >> 3) & 7) * 128;
  const int t = threadIdx.x;
  const int lane = t & 63, wid = t >> 6;
  const int wr = wid >> 1, wc = wid & 1;
  const int g = lane >> 4, r16 = lane & 15;

  const int lrow = lane >> 2;
  const int lchunk = (lane & 3) ^ ((lane >> 3) & 3);
  const int u0 = 2 * wid;
  int ar0 = bm0 + 16 * u0 + lrow, ar1 = ar0 + 16;
  if (srcmap) {
    ar0 = srcmap[ar0];
    ar1 = srcmap[ar1];
  }
  const int br0 = bn0 + 16 * u0 + lrow, br1 = br0 + 16;
  const u16* aSh0 = Ahp + (size_t)ar0 * D_DIM + lchunk * 8;
  const u16* aSh1 = Ahp + (size_t)ar1 * D_DIM + lchunk * 8;
  const u16* aSl0 = Alp + (size_t)ar0 * D_DIM + lchunk * 8;
  const u16* aSl1 = Alp + (size_t)ar1 * D_DIM + lchunk * 8;
  const u16* bSh0 = Bhp + (size_t)br0 * D_DIM + lchunk * 8;
  const u16* bSh1 = Bhp + (size_t)br1 * D_DIM + lchunk * 8;
  const u16* bSl0 = Blp + (size_t)br0 * D_DIM + lchunk * 8;
  const u16* bSl1 = Blp + (size_t)br1 * D_DIM + lchunk * 8;
  const int dst0 = u0 * 512 + lane * 8, dst1 = dst0 + 512;

  const int fsw = ((g ^ (r16 >> 1)) & 3) * 8;
  int a_rd[4], b_rd[4];
#pragma unroll
  for (int i = 0; i < 4; ++i) {
    a_rd[i] = (wr * 64 + i * 16 + r16) * 32 + fsw;
    b_rd[i] = 8192 + (wc * 64 + i * 16 + r16) * 32 + fsw;
  }

  f32x4 acc[4][4];
#pragma unroll
  for (int i = 0; i < 4; ++i)
#pragma unroll
    for (int j = 0; j < 4; ++j) acc[i][j] = (f32x4)0.0f;

  auto stage = [&](int kt) {
    const int k0 = kt << 5;
    u16* db = lds + (kt & 1) * 16384;
    glds16(aSh0 + k0, db + dst0);
    glds16(aSh1 + k0, db + dst1);
    glds16(aSl0 + k0, db + 4096 + dst0);
    glds16(aSl1 + k0, db + 4096 + dst1);
    glds16(bSh0 + k0, db + 8192 + dst0);
    glds16(bSh1 + k0, db + 8192 + dst1);
    glds16(bSl0 + k0, db + 12288 + dst0);
    glds16(bSl1 + k0, db + 12288 + dst1);
  };
  stage(0);

#pragma unroll 1
  for (int kt = 0; kt < NKT; ++kt) {
    asm volatile("s_waitcnt vmcnt(0)" ::: "memory");
    __builtin_amdgcn_s_barrier();
    asm volatile("" ::: "memory");
    const u16* Lb = lds + (kt & 1) * 16384;
    if (kt + 1 < NKT) stage(kt + 1);
    short8 ah[4], al[4], bh[4], bl[4];
#pragma unroll
    for (int i = 0; i < 4; ++i) {
      ah[i] = *(const short8*)(Lb + a_rd[i]);
      bh[i] = *(const short8*)(Lb + b_rd[i]);
    }
    __builtin_amdgcn_s_setprio(1);
#pragma unroll
    for (int i = 0; i < 4; ++i)
#pragma unroll
      for (int n = 0; n < 4; ++n) acc[i][n] = mfma16(ah[i], bh[n], acc[i][n]);
    __builtin_amdgcn_s_setprio(0);
#pragma unroll
    for (int i = 0; i < 4; ++i) {
      al[i] = *(const short8*)(Lb + 4096 + a_rd[i]);
      bl[i] = *(const short8*)(Lb + 4096 + b_rd[i]);
    }
    __builtin_amdgcn_s_setprio(1);
#pragma unroll
    for (int i = 0; i < 4; ++i)
#pragma unroll
      for (int n = 0; n < 4; ++n) acc[i][n] = mfma16(ah[i], bl[n], acc[i][n]);
#pragma unroll
    for (int i = 0; i < 4; ++i)
#pragma unroll
      for (int n = 0; n < 4; ++n) acc[i][n] = mfma16(al[i], bh[n], acc[i][n]);
    __builtin_amdgcn_s_setprio(0);
  }

  __syncthreads();

  float bv[4], hwv[4];
#pragma unroll
  for (int ni = 0; ni < 4; ++ni) {
    int col = bn0 + wc * 64 + ni * 16 + r16;
    bv[ni] = bias[col];
    hwv[ni] = halt_w[col];
  }
  float zp[4][4];
#pragma unroll
  for (int mi = 0; mi < 4; ++mi)
#pragma unroll
    for (int j = 0; j < 4; ++j) {
      float zz = 0.0f;
#pragma unroll
      for (int ni = 0; ni < 4; ++ni) {
        float v = gelu_f(acc[mi][ni][j] + bv[ni]);
        acc[mi][ni][j] = v;
        zz += v * hwv[ni];
      }
      zp[mi][j] = zz;
    }
#pragma unroll
  for (int off = 1; off < 16; off <<= 1)
#pragma unroll
    for (int mi = 0; mi < 4; ++mi)
#pragma unroll
      for (int j = 0; j < 4; ++j) zp[mi][j] += __shfl_xor(zp[mi][j], off);
  float* zf = (float*)lds;  // [2][128]
  if (r16 == 0) {
#pragma unroll
    for (int mi = 0; mi < 4; ++mi)
#pragma unroll
      for (int j = 0; j < 4; ++j)
        zf[wc * 128 + wr * 64 + mi * 16 + g * 4 + j] = zp[mi][j];
  }
  __syncthreads();
  if (t < 128) zpart[(size_t)(bn0 >> 7) * M + bm0 + t] = zf[t] + zf[128 + t];
  __syncthreads();

  u16* hp = lds;
#pragma unroll
  for (int mi = 0; mi < 4; ++mi)
#pragma unroll
    for (int ni = 0; ni < 4; ++ni)
#pragma unroll
      for (int j = 0; j < 4; ++j)
        hp[(wr * 64 + mi * 16 + g * 4 + j) * 128 + wc * 64 + ni * 16 + r16] =
            f2bf(acc[mi][ni][j]);
  __syncthreads();
#pragma unroll
  for (int p = 0; p < 8; ++p) {
    int idx = p * 256 + t;
    int r = idx >> 4, c = idx & 15;
    *(short8*)(Hh + (size_t)(bm0 + r) * D_DIM + bn0 + c * 8) =
        *(const short8*)&hp[r * 128 + c * 8];
  }
  if (writeLo) {
    __syncthreads();
#pragma unroll
    for (int mi = 0; mi < 4; ++mi)
#pragma unroll
      for (int ni = 0; ni < 4; ++ni)
#pragma unroll
        for (int j = 0; j < 4; ++j) {
          float v = acc[mi][ni][j];
          hp[(wr * 64 + mi * 16 + g * 4 + j) * 128 + wc * 64 + ni * 16 + r16] =
              f2bf(v - bf2f(f2bf(v)));
        }
    __syncthreads();
#pragma unroll
    for (int p = 0; p < 8; ++p) {
      int idx = p * 256 + t;
      int r = idx >> 4, c = idx & 15;
      *(short8*)(Hl + (size_t)(bm0 + r) * D_DIM + bn0 + c * 8) =
          *(const short8*)&hp[r * 128 + c * 8];
    }
  }
}

// ---------------- ACT scalar kernels (round-13 structure) ----------------
__global__ __launch_bounds__(256) void act_weights_kernel(
    const float* __restrict__ zpart, const float* __restrict__ halt_b,
    float* __restrict__ cum, float* __restrict__ rem, float* __restrict__ pond,
    float* __restrict__ wout, float* __restrict__ wfull,
    int* __restrict__ slotmap, int* __restrict__ last_step,
    const int* __restrict__ idx, const int* __restrict__ np, int step,
    int last, int M) {
  int slot = blockIdx.x * 256 + threadIdx.x;
  if (slot >= *np) return;
  int tok = idx ? idx[slot] : slot;
  float z = halt_b[0];
#pragma unroll
  for (int nb = 0; nb < 8; ++nb) z += zpart[(size_t)nb * M + slot];
  float p = 1.0f / (1.0f + expf(-z));
  float c, r, q;
  if (step == 0) {
    c = 0.0f; r = 1.0f; q = 0.0f;
  } else {
    c = cum[tok]; r = rem[tok]; q = pond[tok];
  }
  float weight = last ? r : (((c + p) >= 0.99f) ? r : p);
  q += weight;
  c += weight;
  r = fmaxf(1.0f - c, 0.0f);
  cum[tok] = c;
  rem[tok] = r;
  pond[tok] = q;
  wout[slot] = weight;
  wfull[(size_t)step * M + tok] = weight;
  slotmap[(size_t)step * M + tok] = slot;
  last_step[tok] = step;
}

__global__ __launch_bounds__(1024) void compact_kernel(
    const float* __restrict__ rem, const int* __restrict__ idx_cur,
    const int* __restrict__ ncur_p, int* __restrict__ idx_next,
    int* __restrict__ src_next, int* __restrict__ cnt_next) {
  __shared__ int sc[1024];
  const int t = threadIdx.x;
  const int n = *ncur_p;
  const int base = t * 16;
  int lc = 0;
#pragma unroll
  for (int i = 0; i < 16; ++i) {
    int j = base + i;
    if (j < n) {
      int tok = idx_cur ? idx_cur[j] : j;
      if (rem[tok] > 0.0f) ++lc;
    }
  }
  sc[t] = lc;
  __syncthreads();
  for (int d = 1; d < 1024; d <<= 1) {
    int v = (t >= d) ? sc[t - d] : 0;
    __syncthreads();
    sc[t] += v;
    __syncthreads();
  }
  int pos = sc[t] - lc;
  const int total = sc[1023];
#pragma unroll
  for (int i = 0; i < 16; ++i) {
    int j = base + i;
    if (j < n) {
      int tok = idx_cur ? idx_cur[j] : j;
      if (rem[tok] > 0.0f) {
        idx_next[pos] = tok;
        src_next[pos] = j;
        ++pos;
      }
    }
  }
  if (t == 0) {
    int pad = (total + 127) & ~127;
    cnt_next[0] = total;
    cnt_next[1] = pad;
    for (int j = total; j < pad; ++j) {
      idx_next[j] = -1;
      src_next[j] = 0;
    }
  }
}

// Fallback per-step: out[tok] (+)= w[slot] * h[slot]   (hi plane only)
__global__ __launch_bounds__(256) void act_out_kernel(
    const u16* __restrict__ h, const float* __restrict__ w,
    const int* __restrict__ idx, const int* __restrict__ np, int accum,
    float* __restrict__ out) {
  size_t gid = (size_t)blockIdx.x * 256 + threadIdx.x;
  int slot = (int)(gid >> 7);
  if (slot >= *np) return;
  int off = ((int)gid & 127) * 8;
  int tok = idx ? idx[slot] : slot;
  size_t hb = (size_t)slot * D_DIM + off;
  size_t ob = (size_t)tok * D_DIM + off;
  float ws = w[slot];
  short8 hi = *(const short8*)(h + hb);
  float o[8];
  if (accum) {
    float4 a = *(const float4*)(out + ob);
    float4 b = *(const float4*)(out + ob + 4);
    o[0] = a.x; o[1] = a.y; o[2] = a.z; o[3] = a.w;
    o[4] = b.x; o[5] = b.y; o[6] = b.z; o[7] = b.w;
  } else {
#pragma unroll
    for (int j = 0; j < 8; ++j) o[j] = 0.0f;
  }
#pragma unroll
  for (int j = 0; j < 8; ++j) o[j] += ws * bf2f((u16)hi[j]);
  *(float4*)(out + ob) = make_float4(o[0], o[1], o[2], o[3]);
  *(float4*)(out + ob + 4) = make_float4(o[4], o[5], o[6], o[7]);
}

// Deferred: out[tok] = sum_{s<=ls} wfull[s][tok] * H_{s+1}[slotmap[s][tok]]
__global__ __launch_bounds__(256) void act_out_final_kernel(
    const u16* __restrict__ h1, const u16* __restrict__ h2,
    const u16* __restrict__ h3, const u16* __restrict__ h4,
    const float* __restrict__ wfull, const int* __restrict__ slotmap,
    const int* __restrict__ last_step, float* __restrict__ out, int M) {
  size_t gid = (size_t)blockIdx.x * 256 + threadIdx.x;
  int tok = (int)(gid >> 7);
  int off = ((int)gid & 127) * 8;
  const int ls = last_step[tok];
  float o[8];
#pragma unroll
  for (int j = 0; j < 8; ++j) o[j] = 0.0f;
  for (int s = 0; s <= ls; ++s) {
    int slot = slotmap[(size_t)s * M + tok];
    float w = wfull[(size_t)s * M + tok];
    const u16* b = (s == 0) ? h1 : (s == 1) ? h2 : (s == 2) ? h3 : h4;
    short8 hv = *(const short8*)(b + (size_t)slot * D_DIM + off);
#pragma unroll
    for (int j = 0; j < 8; ++j) o[j] += w * bf2f((u16)hv[j]);
  }
  size_t ob = (size_t)tok * D_DIM + off;
  *(float4*)(out + ob) = make_float4(o[0], o[1], o[2], o[3]);
  *(float4*)(out + ob + 4) = make_float4(o[4], o[5], o[6], o[7]);
}

__global__ __launch_bounds__(256) void ponder_reduce_kernel(
    const float* __restrict__ pond, float* __restrict__ o, int n) {
  __shared__ float sh[256];
  float a = 0.0f;
  for (int i = threadIdx.x; i < n; i += 256) a += pond[i];
  sh[threadIdx.x] = a;
  __syncthreads();
  for (int s = 128; s; s >>= 1) {
    if ((int)threadIdx.x < s) sh[threadIdx.x] += sh[threadIdx.x + s];
    __syncthreads();
  }
  if (threadIdx.x == 0) o[0] = sh[0] / (float)n;
}

extern "C" void kernel_launch(void* const* d_in, const int* in_sizes, int n_in,
                              void* d_out, int out_size, void* d_ws,
                              size_t ws_size, hipStream_t stream) {
  const float* x = (const float*)d_in[0];
  const float* layer_w = (const float*)d_in[1];
  const float* layer_b = (const float*)d_in[2];
  const float* halt_w = (const float*)d_in[3];
  const float* halt_b = (const float*)d_in[4];
  float* out = (float*)d_out;

  const int D = D_DIM;
  const int M = in_sizes[0] / D;        // 16384
  const int L = in_sizes[1] / (D * D);  // 4
  const size_t MD = (size_t)M * D, DD = (size_t)D * D;

  char* ws = (char*)d_ws;
  size_t off = 0;
  auto alloc = [&](size_t bytes) {
    void* p = ws + off;
    off += (bytes + 255) & ~(size_t)255;
    return p;
  };
  u16* Wsplit = (u16*)alloc((size_t)L * 2 * DD * sizeof(u16));  // hi | lo
  float* zpart = (float*)alloc(8 * (size_t)M * 4);
  float* wbuf = (float*)alloc((size_t)M * 4);
  float* wfull = (float*)alloc((size_t)L * M * 4);
  int* slotmap = (int*)alloc((size_t)L * M * 4);
  int* last_step = (int*)alloc((size_t)M * 4);
  float* cum = (float*)alloc((size_t)M * 4);
  float* rem = (float*)alloc((size_t)M * 4);
  float* pond = (float*)alloc((size_t)M * 4);
  int* counts = (int*)alloc(16 * sizeof(int));  // [2s]=exact, [2s+1]=pad
  int* idxA = (int*)alloc((size_t)M * 4);
  int* idxB = (int*)alloc((size_t)M * 4);
  int* srcb = (int*)alloc((size_t)M * 4);

  // planes: x pair always; deferred adds 2 archive hi planes + 2 lo planes
  // (A3/A4 overlay the dead x pair); fallback adds one full pair.
  u16* xpair = (u16*)alloc(2 * MD * sizeof(u16));  // [xh | xl]
  const bool deferred = (off + 2 * (2 * MD * sizeof(u16)) + 4096) <= ws_size;
  u16 *arch = nullptr, *lopp = nullptr, *P1 = nullptr;
  if (deferred) {
    arch = (u16*)alloc(2 * MD * sizeof(u16));  // A1 | A2
    lopp = (u16*)alloc(2 * MD * sizeof(u16));  // LB0 | LB1
  } else {
    P1 = (u16*)alloc(2 * MD * sizeof(u16));
  }
  u16* A[5] = {nullptr, arch, arch ? arch + MD : nullptr, xpair, xpair + MD};

  hipFuncSetAttribute((const void*)gemm_act_kernel,
                      hipFuncAttributeMaxDynamicSharedMemorySize, 65536);

  prep_kernel<<<(unsigned)(1024 + MD / 1024), 256, 0, stream>>>(
      layer_w, Wsplit, Wsplit + (size_t)L * DD, x, xpair, xpair + MD, counts,
      M);

  for (int s = 0; s < L; ++s) {
    const int* idxs = (s == 0) ? nullptr : ((s & 1) ? idxB : idxA);
    const u16 *Ahp, *Alp;
    u16 *Hh, *Hl;
    if (deferred) {
      Ahp = (s == 0) ? xpair : A[s];
      Alp = (s == 0) ? (xpair + MD) : (lopp + (size_t)((s - 1) & 1) * MD);
      Hh = A[s + 1];
      Hl = lopp + (size_t)(s & 1) * MD;
    } else {
      u16* pin = (s & 1) ? P1 : xpair;
      u16* pout = (s & 1) ? xpair : P1;
      Ahp = pin;
      Alp = pin + MD;
      Hh = pout;
      Hl = pout + MD;
    }
    gemm_act_kernel<<<dim3((M / 128) * (D / 128)), 256, 65536, stream>>>(
        Ahp, Alp, Wsplit + (size_t)s * DD, Wsplit + (size_t)(L + s) * DD,
        layer_b + (size_t)s * D, halt_w, Hh, Hl, zpart,
        (s == 0) ? nullptr : srcb, counts + 2 * s + 1, M,
        (s < L - 1) ? 1 : 0);
    act_weights_kernel<<<M / 256, 256, 0, stream>>>(
        zpart, halt_b, cum, rem, pond, wbuf, wfull, slotmap, last_step, idxs,
        counts + 2 * s, s, (s == L - 1) ? 1 : 0, M);
    if (!deferred)
      act_out_kernel<<<(unsigned)(MD / 2048), 256, 0, stream>>>(
          Hh, wbuf, idxs, counts + 2 * s, (s > 0) ? 1 : 0, out);
    if (s + 1 < L) {
      int* idxn = ((s + 1) & 1) ? idxB : idxA;
      compact_kernel<<<1, 1024, 0, stream>>>(rem, idxs, counts + 2 * s, idxn,
                                             srcb, counts + 2 * (s + 1));
    }
  }
  if (deferred)
    act_out_final_kernel<<<(unsigned)(MD / 2048), 256, 0, stream>>>(
        A[1], A[2], A[3], A[4], wfull, slotmap, last_step, out, M);
  ponder_reduce_kernel<<<1, 256, 0, stream>>>(pond, out + MD, M);
}

// Round 17
// 374.065 us; speedup vs baseline: 2.4923x; 1.2380x over previous
//
#include <hip/hip_runtime.h>

typedef __attribute__((ext_vector_type(8))) short short8;
typedef __attribute__((ext_vector_type(4))) float f32x4;
typedef __attribute__((ext_vector_type(4))) unsigned short u16x4;
typedef unsigned short u16;

#define D_DIM 1024
#define NKT 32  // K / 32

__device__ __forceinline__ u16 f2bf(float f) {
  unsigned u = __builtin_bit_cast(unsigned, f);
  u += 0x7fffu + ((u >> 16) & 1u);
  return (u16)(u >> 16);
}
__device__ __forceinline__ float bf2f(u16 b) {
  return __builtin_bit_cast(float, ((unsigned)b) << 16);
}
__device__ __forceinline__ float gelu_f(float x) {
  float i = 0.7978845608028654f * (x + 0.044715f * x * x * x);
  float ex = __builtin_amdgcn_exp2f(i * 2.885390081777927f);  // e^{2i}
  float th = 1.0f - 2.0f * __builtin_amdgcn_rcpf(ex + 1.0f);
  return 0.5f * x * (1.0f + th);
}
__device__ __forceinline__ f32x4 mfma16(short8 a, short8 b, f32x4 c) {
  return __builtin_amdgcn_mfma_f32_16x16x32_bf16(a, b, c, 0, 0, 0);
}
__device__ __forceinline__ void glds16(const u16* g, const u16* l) {
  __builtin_amdgcn_global_load_lds(
      (const __attribute__((address_space(1))) void*)g,
      (__attribute__((address_space(3))) void*)l, 16, 0, 0);
}

// ---------------- fused prep: W split+transpose (blocks 0..1023) and
// x hi split (blocks 1024..) ----------------
__global__ __launch_bounds__(256) void prep_kernel(
    const float* __restrict__ W, u16* __restrict__ Wth, u16* __restrict__ Wtl,
    const float* __restrict__ x, u16* __restrict__ xh, int* __restrict__ counts,
    int M) {
  __shared__ float tile[64][65];
  const int bid = blockIdx.x;
  const int t = threadIdx.x;
  if (bid < 1024) {
    const int k0 = (bid & 15) * 64, n0 = ((bid >> 4) & 15) * 64;
    const size_t lbase = (size_t)(bid >> 8) * D_DIM * D_DIM;
#pragma unroll
    for (int j = 0; j < 16; ++j) {
      int idx = t + 256 * j;
      int r = idx >> 6, c = idx & 63;
      tile[r][c] = W[lbase + (size_t)(k0 + r) * D_DIM + (n0 + c)];
    }
    __syncthreads();
#pragma unroll
    for (int j = 0; j < 16; ++j) {
      int idx = t + 256 * j;
      int r = idx >> 6, c = idx & 63;
      float f = tile[c][r];
      u16 hb = f2bf(f);
      u16 lb = f2bf(f - bf2f(hb));
      size_t oidx = lbase + (size_t)(n0 + r) * D_DIM + (k0 + c);
      Wth[oidx] = hb;
      Wtl[oidx] = lb;
    }
  } else {
    if (bid == 1024 && t == 0) {
      counts[0] = M;  // exact count, layer 0
      counts[1] = M;  // padded count, layer 0
    }
    size_t i = ((size_t)(bid - 1024) * 256 + t) * 4;
    const float4 v = *(const float4*)(x + i);
    const float fv[4] = {v.x, v.y, v.z, v.w};
    u16x4 h4;
#pragma unroll
    for (int c = 0; c < 4; ++c) h4[c] = f2bf(fv[c]);
    *(u16x4*)(xh + i) = h4;
  }
}

// ---------------- 128x128 gather-GEMM + ACT epilogue ----------------
// Split GEMM with 2 products: AhBh + AhBl (A-lo term dropped; error ~2e-3
// in z, well under the 7.9e-2 budget). LDS buffer (12288 u16 = 24 KB):
// Ah[128][32] | Bh | Bl; dbuf 48 KB -> 3 blocks/CU. 16B slot s of row r
// holds k-chunk s ^ ((r>>1)&3) (bank-uniform). XCD map mt=(bid&7)+8*(bid>>6)
// spreads front-packed active tiles; early-exit on padded active count.
__global__ __launch_bounds__(256, 3) void gemm_act_kernel(
    const u16* __restrict__ Ahp, const u16* __restrict__ Bhp,
    const u16* __restrict__ Blp, const float* __restrict__ bias,
    const float* __restrict__ halt_w, u16* __restrict__ Hh,
    float* __restrict__ zpart, const int* __restrict__ srcmap,
    const int* __restrict__ npadp, int M) {
  extern __shared__ u16 lds[];  // 2 x 12288 u16 = 48 KB
  const int bid = blockIdx.x;   // 1024 blocks
  const int mt = (bid & 7) + 8 * (bid >> 6);
  const int bm0 = mt * 128;
  if (bm0 >= *npadp) return;
  const int bn0 = ((bid >> 3) & 7) * 128;
  const int t = threadIdx.x;
  const int lane = t & 63, wid = t >> 6;
  const int wr = wid >> 1, wc = wid & 1;
  const int g = lane >> 4, r16 = lane & 15;

  const int lrow = lane >> 2;
  const int lchunk = (lane & 3) ^ ((lane >> 3) & 3);
  const int u0 = 2 * wid;
  int ar0 = bm0 + 16 * u0 + lrow, ar1 = ar0 + 16;
  if (srcmap) {
    ar0 = srcmap[ar0];
    ar1 = srcmap[ar1];
  }
  const int br0 = bn0 + 16 * u0 + lrow, br1 = br0 + 16;
  const u16* aSh0 = Ahp + (size_t)ar0 * D_DIM + lchunk * 8;
  const u16* aSh1 = Ahp + (size_t)ar1 * D_DIM + lchunk * 8;
  const u16* bSh0 = Bhp + (size_t)br0 * D_DIM + lchunk * 8;
  const u16* bSh1 = Bhp + (size_t)br1 * D_DIM + lchunk * 8;
  const u16* bSl0 = Blp + (size_t)br0 * D_DIM + lchunk * 8;
  const u16* bSl1 = Blp + (size_t)br1 * D_DIM + lchunk * 8;
  const int dst0 = u0 * 512 + lane * 8, dst1 = dst0 + 512;

  const int fsw = ((g ^ (r16 >> 1)) & 3) * 8;
  int a_rd[4], b_rd[4];
#pragma unroll
  for (int i = 0; i < 4; ++i) {
    a_rd[i] = (wr * 64 + i * 16 + r16) * 32 + fsw;
    b_rd[i] = 4096 + (wc * 64 + i * 16 + r16) * 32 + fsw;
  }

  f32x4 acc[4][4];
#pragma unroll
  for (int i = 0; i < 4; ++i)
#pragma unroll
    for (int j = 0; j < 4; ++j) acc[i][j] = (f32x4)0.0f;

  auto stage = [&](int kt) {
    const int k0 = kt << 5;
    u16* db = lds + (kt & 1) * 12288;
    glds16(aSh0 + k0, db + dst0);
    glds16(aSh1 + k0, db + dst1);
    glds16(bSh0 + k0, db + 4096 + dst0);
    glds16(bSh1 + k0, db + 4096 + dst1);
    glds16(bSl0 + k0, db + 8192 + dst0);
    glds16(bSl1 + k0, db + 8192 + dst1);
  };
  stage(0);

#pragma unroll 1
  for (int kt = 0; kt < NKT; ++kt) {
    asm volatile("s_waitcnt vmcnt(0)" ::: "memory");
    __builtin_amdgcn_s_barrier();
    asm volatile("" ::: "memory");
    const u16* Lb = lds + (kt & 1) * 12288;
    if (kt + 1 < NKT) stage(kt + 1);
    short8 ah[4], bh[4], bl[4];
#pragma unroll
    for (int i = 0; i < 4; ++i) {
      ah[i] = *(const short8*)(Lb + a_rd[i]);
      bh[i] = *(const short8*)(Lb + b_rd[i]);
    }
    __builtin_amdgcn_s_setprio(1);
#pragma unroll
    for (int i = 0; i < 4; ++i)
#pragma unroll
      for (int n = 0; n < 4; ++n) acc[i][n] = mfma16(ah[i], bh[n], acc[i][n]);
    __builtin_amdgcn_s_setprio(0);
#pragma unroll
    for (int i = 0; i < 4; ++i) bl[i] = *(const short8*)(Lb + 4096 + b_rd[i]);
    __builtin_amdgcn_s_setprio(1);
#pragma unroll
    for (int i = 0; i < 4; ++i)
#pragma unroll
      for (int n = 0; n < 4; ++n) acc[i][n] = mfma16(ah[i], bl[n], acc[i][n]);
    __builtin_amdgcn_s_setprio(0);
  }

  __syncthreads();

  float bv[4], hwv[4];
#pragma unroll
  for (int ni = 0; ni < 4; ++ni) {
    int col = bn0 + wc * 64 + ni * 16 + r16;
    bv[ni] = bias[col];
    hwv[ni] = halt_w[col];
  }
  float zp[4][4];
#pragma unroll
  for (int mi = 0; mi < 4; ++mi)
#pragma unroll
    for (int j = 0; j < 4; ++j) {
      float zz = 0.0f;
#pragma unroll
      for (int ni = 0; ni < 4; ++ni) {
        float v = gelu_f(acc[mi][ni][j] + bv[ni]);
        acc[mi][ni][j] = v;
        zz += v * hwv[ni];
      }
      zp[mi][j] = zz;
    }
#pragma unroll
  for (int off = 1; off < 16; off <<= 1)
#pragma unroll
    for (int mi = 0; mi < 4; ++mi)
#pragma unroll
      for (int j = 0; j < 4; ++j) zp[mi][j] += __shfl_xor(zp[mi][j], off);
  float* zf = (float*)lds;  // [2][128]
  if (r16 == 0) {
#pragma unroll
    for (int mi = 0; mi < 4; ++mi)
#pragma unroll
      for (int j = 0; j < 4; ++j)
        zf[wc * 128 + wr * 64 + mi * 16 + g * 4 + j] = zp[mi][j];
  }
  __syncthreads();
  if (t < 128) zpart[(size_t)(bn0 >> 7) * M + bm0 + t] = zf[t] + zf[128 + t];
  __syncthreads();

  u16* hp = lds;  // [128][128] u16 = 32 KB (< 48 KB declared)
#pragma unroll
  for (int mi = 0; mi < 4; ++mi)
#pragma unroll
    for (int ni = 0; ni < 4; ++ni)
#pragma unroll
      for (int j = 0; j < 4; ++j)
        hp[(wr * 64 + mi * 16 + g * 4 + j) * 128 + wc * 64 + ni * 16 + r16] =
            f2bf(acc[mi][ni][j]);
  __syncthreads();
#pragma unroll
  for (int p = 0; p < 8; ++p) {
    int idx = p * 256 + t;
    int r = idx >> 4, c = idx & 15;
    *(short8*)(Hh + (size_t)(bm0 + r) * D_DIM + bn0 + c * 8) =
        *(const short8*)&hp[r * 128 + c * 8];
  }
}

// ---------------- ACT scalar kernels (round-13 structure) ----------------
__global__ __launch_bounds__(256) void act_weights_kernel(
    const float* __restrict__ zpart, const float* __restrict__ halt_b,
    float* __restrict__ cum, float* __restrict__ rem, float* __restrict__ pond,
    float* __restrict__ wout, float* __restrict__ wfull,
    int* __restrict__ slotmap, int* __restrict__ last_step,
    const int* __restrict__ idx, const int* __restrict__ np, int step,
    int last, int M) {
  int slot = blockIdx.x * 256 + threadIdx.x;
  if (slot >= *np) return;
  int tok = idx ? idx[slot] : slot;
  float z = halt_b[0];
#pragma unroll
  for (int nb = 0; nb < 8; ++nb) z += zpart[(size_t)nb * M + slot];
  float p = 1.0f / (1.0f + expf(-z));
  float c, r, q;
  if (step == 0) {
    c = 0.0f; r = 1.0f; q = 0.0f;
  } else {
    c = cum[tok]; r = rem[tok]; q = pond[tok];
  }
  float weight = last ? r : (((c + p) >= 0.99f) ? r : p);
  q += weight;
  c += weight;
  r = fmaxf(1.0f - c, 0.0f);
  cum[tok] = c;
  rem[tok] = r;
  pond[tok] = q;
  wout[slot] = weight;
  wfull[(size_t)step * M + tok] = weight;
  slotmap[(size_t)step * M + tok] = slot;
  last_step[tok] = step;
}

__global__ __launch_bounds__(1024) void compact_kernel(
    const float* __restrict__ rem, const int* __restrict__ idx_cur,
    const int* __restrict__ ncur_p, int* __restrict__ idx_next,
    int* __restrict__ src_next, int* __restrict__ cnt_next) {
  __shared__ int sc[1024];
  const int t = threadIdx.x;
  const int n = *ncur_p;
  const int base = t * 16;
  int lc = 0;
#pragma unroll
  for (int i = 0; i < 16; ++i) {
    int j = base + i;
    if (j < n) {
      int tok = idx_cur ? idx_cur[j] : j;
      if (rem[tok] > 0.0f) ++lc;
    }
  }
  sc[t] = lc;
  __syncthreads();
  for (int d = 1; d < 1024; d <<= 1) {
    int v = (t >= d) ? sc[t - d] : 0;
    __syncthreads();
    sc[t] += v;
    __syncthreads();
  }
  int pos = sc[t] - lc;
  const int total = sc[1023];
#pragma unroll
  for (int i = 0; i < 16; ++i) {
    int j = base + i;
    if (j < n) {
      int tok = idx_cur ? idx_cur[j] : j;
      if (rem[tok] > 0.0f) {
        idx_next[pos] = tok;
        src_next[pos] = j;
        ++pos;
      }
    }
  }
  if (t == 0) {
    int pad = (total + 127) & ~127;
    cnt_next[0] = total;
    cnt_next[1] = pad;
    for (int j = total; j < pad; ++j) {
      idx_next[j] = -1;
      src_next[j] = 0;
    }
  }
}

// Fallback per-step: out[tok] (+)= w[slot] * h[slot]
__global__ __launch_bounds__(256) void act_out_kernel(
    const u16* __restrict__ h, const float* __restrict__ w,
    const int* __restrict__ idx, const int* __restrict__ np, int accum,
    float* __restrict__ out) {
  size_t gid = (size_t)blockIdx.x * 256 + threadIdx.x;
  int slot = (int)(gid >> 7);
  if (slot >= *np) return;
  int off = ((int)gid & 127) * 8;
  int tok = idx ? idx[slot] : slot;
  size_t hb = (size_t)slot * D_DIM + off;
  size_t ob = (size_t)tok * D_DIM + off;
  float ws = w[slot];
  short8 hi = *(const short8*)(h + hb);
  float o[8];
  if (accum) {
    float4 a = *(const float4*)(out + ob);
    float4 b = *(const float4*)(out + ob + 4);
    o[0] = a.x; o[1] = a.y; o[2] = a.z; o[3] = a.w;
    o[4] = b.x; o[5] = b.y; o[6] = b.z; o[7] = b.w;
  } else {
#pragma unroll
    for (int j = 0; j < 8; ++j) o[j] = 0.0f;
  }
#pragma unroll
  for (int j = 0; j < 8; ++j) o[j] += ws * bf2f((u16)hi[j]);
  *(float4*)(out + ob) = make_float4(o[0], o[1], o[2], o[3]);
  *(float4*)(out + ob + 4) = make_float4(o[4], o[5], o[6], o[7]);
}

// Deferred: out[tok] = sum_{s<=ls} wfull[s][tok] * H_{s+1}[slotmap[s][tok]]
__global__ __launch_bounds__(256) void act_out_final_kernel(
    const u16* __restrict__ h1, const u16* __restrict__ h2,
    const u16* __restrict__ h3, const u16* __restrict__ h4,
    const float* __restrict__ wfull, const int* __restrict__ slotmap,
    const int* __restrict__ last_step, float* __restrict__ out, int M) {
  size_t gid = (size_t)blockIdx.x * 256 + threadIdx.x;
  int tok = (int)(gid >> 7);
  int off = ((int)gid & 127) * 8;
  const int ls = last_step[tok];
  float o[8];
#pragma unroll
  for (int j = 0; j < 8; ++j) o[j] = 0.0f;
  for (int s = 0; s <= ls; ++s) {
    int slot = slotmap[(size_t)s * M + tok];
    float w = wfull[(size_t)s * M + tok];
    const u16* b = (s == 0) ? h1 : (s == 1) ? h2 : (s == 2) ? h3 : h4;
    short8 hv = *(const short8*)(b + (size_t)slot * D_DIM + off);
#pragma unroll
    for (int j = 0; j < 8; ++j) o[j] += w * bf2f((u16)hv[j]);
  }
  size_t ob = (size_t)tok * D_DIM + off;
  *(float4*)(out + ob) = make_float4(o[0], o[1], o[2], o[3]);
  *(float4*)(out + ob + 4) = make_float4(o[4], o[5], o[6], o[7]);
}

__global__ __launch_bounds__(256) void ponder_reduce_kernel(
    const float* __restrict__ pond, float* __restrict__ o, int n) {
  __shared__ float sh[256];
  float a = 0.0f;
  for (int i = threadIdx.x; i < n; i += 256) a += pond[i];
  sh[threadIdx.x] = a;
  __syncthreads();
  for (int s = 128; s; s >>= 1) {
    if ((int)threadIdx.x < s) sh[threadIdx.x] += sh[threadIdx.x + s];
    __syncthreads();
  }
  if (threadIdx.x == 0) o[0] = sh[0] / (float)n;
}

extern "C" void kernel_launch(void* const* d_in, const int* in_sizes, int n_in,
                              void* d_out, int out_size, void* d_ws,
                              size_t ws_size, hipStream_t stream) {
  const float* x = (const float*)d_in[0];
  const float* layer_w = (const float*)d_in[1];
  const float* layer_b = (const float*)d_in[2];
  const float* halt_w = (const float*)d_in[3];
  const float* halt_b = (const float*)d_in[4];
  float* out = (float*)d_out;

  const int D = D_DIM;
  const int M = in_sizes[0] / D;        // 16384
  const int L = in_sizes[1] / (D * D);  // 4
  const size_t MD = (size_t)M * D, DD = (size_t)D * D;

  char* ws = (char*)d_ws;
  size_t off = 0;
  auto alloc = [&](size_t bytes) {
    void* p = ws + off;
    off += (bytes + 255) & ~(size_t)255;
    return p;
  };
  u16* Wsplit = (u16*)alloc((size_t)L * 2 * DD * sizeof(u16));  // hi | lo
  float* zpart = (float*)alloc(8 * (size_t)M * 4);
  float* wbuf = (float*)alloc((size_t)M * 4);
  float* wfull = (float*)alloc((size_t)L * M * 4);
  int* slotmap = (int*)alloc((size_t)L * M * 4);
  int* last_step = (int*)alloc((size_t)M * 4);
  float* cum = (float*)alloc((size_t)M * 4);
  float* rem = (float*)alloc((size_t)M * 4);
  float* pond = (float*)alloc((size_t)M * 4);
  int* counts = (int*)alloc(16 * sizeof(int));  // [2s]=exact, [2s+1]=pad
  int* idxA = (int*)alloc((size_t)M * 4);
  int* idxB = (int*)alloc((size_t)M * 4);
  int* srcb = (int*)alloc((size_t)M * 4);

  // hi planes only (A-lo dropped). xpair: slot0 = xh (later A3), slot1 = A4.
  u16* xpair = (u16*)alloc(2 * MD * sizeof(u16));
  const bool deferred = (off + 2 * MD * sizeof(u16) + 4096) <= ws_size;
  u16 *arch = nullptr, *P1 = nullptr;
  if (deferred) {
    arch = (u16*)alloc(2 * MD * sizeof(u16));  // A1 | A2
  } else {
    P1 = (u16*)alloc(MD * sizeof(u16));
  }
  u16* A[5] = {nullptr, arch, arch ? arch + MD : nullptr, xpair, xpair + MD};

  hipFuncSetAttribute((const void*)gemm_act_kernel,
                      hipFuncAttributeMaxDynamicSharedMemorySize, 49152);

  prep_kernel<<<(unsigned)(1024 + MD / 1024), 256, 0, stream>>>(
      layer_w, Wsplit, Wsplit + (size_t)L * DD, x, xpair, counts, M);

  for (int s = 0; s < L; ++s) {
    const int* idxs = (s == 0) ? nullptr : ((s & 1) ? idxB : idxA);
    const u16* Ahp;
    u16* Hh;
    if (deferred) {
      Ahp = (s == 0) ? xpair : A[s];
      Hh = A[s + 1];
    } else {
      Ahp = (s & 1) ? P1 : xpair;
      Hh = (s & 1) ? xpair : P1;
    }
    gemm_act_kernel<<<dim3((M / 128) * (D / 128)), 256, 49152, stream>>>(
        Ahp, Wsplit + (size_t)s * DD, Wsplit + (size_t)(L + s) * DD,
        layer_b + (size_t)s * D, halt_w, Hh, zpart,
        (s == 0) ? nullptr : srcb, counts + 2 * s + 1, M);
    act_weights_kernel<<<M / 256, 256, 0, stream>>>(
        zpart, halt_b, cum, rem, pond, wbuf, wfull, slotmap, last_step, idxs,
        counts + 2 * s, s, (s == L - 1) ? 1 : 0, M);
    if (!deferred)
      act_out_kernel<<<(unsigned)(MD / 2048), 256, 0, stream>>>(
          Hh, wbuf, idxs, counts + 2 * s, (s > 0) ? 1 : 0, out);
    if (s + 1 < L) {
      int* idxn = ((s + 1) & 1) ? idxB : idxA;
      compact_kernel<<<1, 1024, 0, stream>>>(rem, idxs, counts + 2 * s, idxn,
                                             srcb, counts + 2 * (s + 1));
    }
  }
  if (deferred)
    act_out_final_kernel<<<(unsigned)(MD / 2048), 256, 0, stream>>>(
        A[1], A[2], A[3], A[4], wfull, slotmap, last_step, out, M);
  ponder_reduce_kernel<<<1, 256, 0, stream>>>(pond, out + MD, M);
}

// Round 18
// 304.680 us; speedup vs baseline: 3.0599x; 1.2277x over previous
//
#include <hip/hip_runtime.h>

typedef __attribute__((ext_vector_type(8))) short short8;
typedef __attribute__((ext_vector_type(4))) float f32x4;
typedef __attribute__((ext_vector_type(4))) unsigned short u16x4;
typedef unsigned short u16;

#define D_DIM 1024
#define NKT 32  // K / 32

__device__ __forceinline__ u16 f2bf(float f) {
  unsigned u = __builtin_bit_cast(unsigned, f);
  u += 0x7fffu + ((u >> 16) & 1u);
  return (u16)(u >> 16);
}
__device__ __forceinline__ float bf2f(u16 b) {
  return __builtin_bit_cast(float, ((unsigned)b) << 16);
}
__device__ __forceinline__ float gelu_f(float x) {
  float i = 0.7978845608028654f * (x + 0.044715f * x * x * x);
  float ex = __builtin_amdgcn_exp2f(i * 2.885390081777927f);  // e^{2i}
  float th = 1.0f - 2.0f * __builtin_amdgcn_rcpf(ex + 1.0f);
  return 0.5f * x * (1.0f + th);
}
__device__ __forceinline__ f32x4 mfma16(short8 a, short8 b, f32x4 c) {
  return __builtin_amdgcn_mfma_f32_16x16x32_bf16(a, b, c, 0, 0, 0);
}
__device__ __forceinline__ void glds16(const u16* g, const u16* l) {
  __builtin_amdgcn_global_load_lds(
      (const __attribute__((address_space(1))) void*)g,
      (__attribute__((address_space(3))) void*)l, 16, 0, 0);
}

// ---------------- fused prep: W transpose+bf16 round (blocks 0..1023) and
// x bf16 round (blocks 1024..) ----------------
__global__ __launch_bounds__(256) void prep_kernel(
    const float* __restrict__ W, u16* __restrict__ Wth,
    const float* __restrict__ x, u16* __restrict__ xh, int* __restrict__ counts,
    int M) {
  __shared__ float tile[64][65];
  const int bid = blockIdx.x;
  const int t = threadIdx.x;
  if (bid < 1024) {
    const int k0 = (bid & 15) * 64, n0 = ((bid >> 4) & 15) * 64;
    const size_t lbase = (size_t)(bid >> 8) * D_DIM * D_DIM;
#pragma unroll
    for (int j = 0; j < 16; ++j) {
      int idx = t + 256 * j;
      int r = idx >> 6, c = idx & 63;
      tile[r][c] = W[lbase + (size_t)(k0 + r) * D_DIM + (n0 + c)];
    }
    __syncthreads();
#pragma unroll
    for (int j = 0; j < 16; ++j) {
      int idx = t + 256 * j;
      int r = idx >> 6, c = idx & 63;
      Wth[lbase + (size_t)(n0 + r) * D_DIM + (k0 + c)] = f2bf(tile[c][r]);
    }
  } else {
    if (bid == 1024 && t == 0) {
      counts[0] = M;  // exact count, layer 0
      counts[1] = M;  // padded count, layer 0
    }
    size_t i = ((size_t)(bid - 1024) * 256 + t) * 4;
    const float4 v = *(const float4*)(x + i);
    const float fv[4] = {v.x, v.y, v.z, v.w};
    u16x4 h4;
#pragma unroll
    for (int c = 0; c < 4; ++c) h4[c] = f2bf(fv[c]);
    *(u16x4*)(xh + i) = h4;
  }
}

// ---------------- 128x128 gather-GEMM (pure bf16) + ACT epilogue ----------
// Single product AhBh (W-lo dropped; added z error ~2e-3, budget 7.9e-2).
// LDS buffer (8192 u16 = 16 KB): Ah[128][32] | Bh; dbuf 32 KB -> 4 blocks/CU.
// 16B slot s of row r holds k-chunk s ^ ((r>>1)&3) (bank-uniform). XCD map
// mt=(bid&7)+8*(bid>>6) spreads front-packed active tiles; early-exit on
// padded active count.
__global__ __launch_bounds__(256, 4) void gemm_act_kernel(
    const u16* __restrict__ Ahp, const u16* __restrict__ Bhp,
    const float* __restrict__ bias, const float* __restrict__ halt_w,
    u16* __restrict__ Hh, float* __restrict__ zpart,
    const int* __restrict__ srcmap, const int* __restrict__ npadp, int M) {
  extern __shared__ u16 lds[];  // 2 x 8192 u16 = 32 KB
  const int bid = blockIdx.x;   // 1024 blocks
  const int mt = (bid & 7) + 8 * (bid >> 6);
  const int bm0 = mt * 128;
  if (bm0 >= *npadp) return;
  const int bn0 = ((bid >> 3) & 7) * 128;
  const int t = threadIdx.x;
  const int lane = t & 63, wid = t >> 6;
  const int wr = wid >> 1, wc = wid & 1;
  const int g = lane >> 4, r16 = lane & 15;

  const int lrow = lane >> 2;
  const int lchunk = (lane & 3) ^ ((lane >> 3) & 3);
  const int u0 = 2 * wid;
  int ar0 = bm0 + 16 * u0 + lrow, ar1 = ar0 + 16;
  if (srcmap) {
    ar0 = srcmap[ar0];
    ar1 = srcmap[ar1];
  }
  const int br0 = bn0 + 16 * u0 + lrow, br1 = br0 + 16;
  const u16* aSh0 = Ahp + (size_t)ar0 * D_DIM + lchunk * 8;
  const u16* aSh1 = Ahp + (size_t)ar1 * D_DIM + lchunk * 8;
  const u16* bSh0 = Bhp + (size_t)br0 * D_DIM + lchunk * 8;
  const u16* bSh1 = Bhp + (size_t)br1 * D_DIM + lchunk * 8;
  const int dst0 = u0 * 512 + lane * 8, dst1 = dst0 + 512;

  const int fsw = ((g ^ (r16 >> 1)) & 3) * 8;
  int a_rd[4], b_rd[4];
#pragma unroll
  for (int i = 0; i < 4; ++i) {
    a_rd[i] = (wr * 64 + i * 16 + r16) * 32 + fsw;
    b_rd[i] = 4096 + (wc * 64 + i * 16 + r16) * 32 + fsw;
  }

  f32x4 acc[4][4];
#pragma unroll
  for (int i = 0; i < 4; ++i)
#pragma unroll
    for (int j = 0; j < 4; ++j) acc[i][j] = (f32x4)0.0f;

  auto stage = [&](int kt) {
    const int k0 = kt << 5;
    u16* db = lds + (kt & 1) * 8192;
    glds16(aSh0 + k0, db + dst0);
    glds16(aSh1 + k0, db + dst1);
    glds16(bSh0 + k0, db + 4096 + dst0);
    glds16(bSh1 + k0, db + 4096 + dst1);
  };
  stage(0);

#pragma unroll 1
  for (int kt = 0; kt < NKT; ++kt) {
    asm volatile("s_waitcnt vmcnt(0)" ::: "memory");
    __builtin_amdgcn_s_barrier();
    asm volatile("" ::: "memory");
    const u16* Lb = lds + (kt & 1) * 8192;
    if (kt + 1 < NKT) stage(kt + 1);
    short8 ah[4], bh[4];
#pragma unroll
    for (int i = 0; i < 4; ++i) {
      ah[i] = *(const short8*)(Lb + a_rd[i]);
      bh[i] = *(const short8*)(Lb + b_rd[i]);
    }
    __builtin_amdgcn_s_setprio(1);
#pragma unroll
    for (int i = 0; i < 4; ++i)
#pragma unroll
      for (int n = 0; n < 4; ++n) acc[i][n] = mfma16(ah[i], bh[n], acc[i][n]);
    __builtin_amdgcn_s_setprio(0);
  }

  __syncthreads();

  float bv[4], hwv[4];
#pragma unroll
  for (int ni = 0; ni < 4; ++ni) {
    int col = bn0 + wc * 64 + ni * 16 + r16;
    bv[ni] = bias[col];
    hwv[ni] = halt_w[col];
  }
  float zp[4][4];
#pragma unroll
  for (int mi = 0; mi < 4; ++mi)
#pragma unroll
    for (int j = 0; j < 4; ++j) {
      float zz = 0.0f;
#pragma unroll
      for (int ni = 0; ni < 4; ++ni) {
        float v = gelu_f(acc[mi][ni][j] + bv[ni]);
        acc[mi][ni][j] = v;
        zz += v * hwv[ni];
      }
      zp[mi][j] = zz;
    }
#pragma unroll
  for (int off = 1; off < 16; off <<= 1)
#pragma unroll
    for (int mi = 0; mi < 4; ++mi)
#pragma unroll
      for (int j = 0; j < 4; ++j) zp[mi][j] += __shfl_xor(zp[mi][j], off);
  float* zf = (float*)lds;  // [2][128]
  if (r16 == 0) {
#pragma unroll
    for (int mi = 0; mi < 4; ++mi)
#pragma unroll
      for (int j = 0; j < 4; ++j)
        zf[wc * 128 + wr * 64 + mi * 16 + g * 4 + j] = zp[mi][j];
  }
  __syncthreads();
  if (t < 128) zpart[(size_t)(bn0 >> 7) * M + bm0 + t] = zf[t] + zf[128 + t];
  __syncthreads();

  u16* hp = lds;  // [128][128] u16 = 32 KB (= declared)
#pragma unroll
  for (int mi = 0; mi < 4; ++mi)
#pragma unroll
    for (int ni = 0; ni < 4; ++ni)
#pragma unroll
      for (int j = 0; j < 4; ++j)
        hp[(wr * 64 + mi * 16 + g * 4 + j) * 128 + wc * 64 + ni * 16 + r16] =
            f2bf(acc[mi][ni][j]);
  __syncthreads();
#pragma unroll
  for (int p = 0; p < 8; ++p) {
    int idx = p * 256 + t;
    int r = idx >> 4, c = idx & 15;
    *(short8*)(Hh + (size_t)(bm0 + r) * D_DIM + bn0 + c * 8) =
        *(const short8*)&hp[r * 128 + c * 8];
  }
}

// ---------------- ACT scalar kernels (round-13 structure) ----------------
__global__ __launch_bounds__(256) void act_weights_kernel(
    const float* __restrict__ zpart, const float* __restrict__ halt_b,
    float* __restrict__ cum, float* __restrict__ rem, float* __restrict__ pond,
    float* __restrict__ wout, float* __restrict__ wfull,
    int* __restrict__ slotmap, int* __restrict__ last_step,
    const int* __restrict__ idx, const int* __restrict__ np, int step,
    int last, int M) {
  int slot = blockIdx.x * 256 + threadIdx.x;
  if (slot >= *np) return;
  int tok = idx ? idx[slot] : slot;
  float z = halt_b[0];
#pragma unroll
  for (int nb = 0; nb < 8; ++nb) z += zpart[(size_t)nb * M + slot];
  float p = 1.0f / (1.0f + expf(-z));
  float c, r, q;
  if (step == 0) {
    c = 0.0f; r = 1.0f; q = 0.0f;
  } else {
    c = cum[tok]; r = rem[tok]; q = pond[tok];
  }
  float weight = last ? r : (((c + p) >= 0.99f) ? r : p);
  q += weight;
  c += weight;
  r = fmaxf(1.0f - c, 0.0f);
  cum[tok] = c;
  rem[tok] = r;
  pond[tok] = q;
  wout[slot] = weight;
  wfull[(size_t)step * M + tok] = weight;
  slotmap[(size_t)step * M + tok] = slot;
  last_step[tok] = step;
}

__global__ __launch_bounds__(1024) void compact_kernel(
    const float* __restrict__ rem, const int* __restrict__ idx_cur,
    const int* __restrict__ ncur_p, int* __restrict__ idx_next,
    int* __restrict__ src_next, int* __restrict__ cnt_next) {
  __shared__ int sc[1024];
  const int t = threadIdx.x;
  const int n = *ncur_p;
  const int base = t * 16;
  int lc = 0;
#pragma unroll
  for (int i = 0; i < 16; ++i) {
    int j = base + i;
    if (j < n) {
      int tok = idx_cur ? idx_cur[j] : j;
      if (rem[tok] > 0.0f) ++lc;
    }
  }
  sc[t] = lc;
  __syncthreads();
  for (int d = 1; d < 1024; d <<= 1) {
    int v = (t >= d) ? sc[t - d] : 0;
    __syncthreads();
    sc[t] += v;
    __syncthreads();
  }
  int pos = sc[t] - lc;
  const int total = sc[1023];
#pragma unroll
  for (int i = 0; i < 16; ++i) {
    int j = base + i;
    if (j < n) {
      int tok = idx_cur ? idx_cur[j] : j;
      if (rem[tok] > 0.0f) {
        idx_next[pos] = tok;
        src_next[pos] = j;
        ++pos;
      }
    }
  }
  if (t == 0) {
    int pad = (total + 127) & ~127;
    cnt_next[0] = total;
    cnt_next[1] = pad;
    for (int j = total; j < pad; ++j) {
      idx_next[j] = -1;
      src_next[j] = 0;
    }
  }
}

// Fallback per-step: out[tok] (+)= w[slot] * h[slot]
__global__ __launch_bounds__(256) void act_out_kernel(
    const u16* __restrict__ h, const float* __restrict__ w,
    const int* __restrict__ idx, const int* __restrict__ np, int accum,
    float* __restrict__ out) {
  size_t gid = (size_t)blockIdx.x * 256 + threadIdx.x;
  int slot = (int)(gid >> 7);
  if (slot >= *np) return;
  int off = ((int)gid & 127) * 8;
  int tok = idx ? idx[slot] : slot;
  size_t hb = (size_t)slot * D_DIM + off;
  size_t ob = (size_t)tok * D_DIM + off;
  float ws = w[slot];
  short8 hi = *(const short8*)(h + hb);
  float o[8];
  if (accum) {
    float4 a = *(const float4*)(out + ob);
    float4 b = *(const float4*)(out + ob + 4);
    o[0] = a.x; o[1] = a.y; o[2] = a.z; o[3] = a.w;
    o[4] = b.x; o[5] = b.y; o[6] = b.z; o[7] = b.w;
  } else {
#pragma unroll
    for (int j = 0; j < 8; ++j) o[j] = 0.0f;
  }
#pragma unroll
  for (int j = 0; j < 8; ++j) o[j] += ws * bf2f((u16)hi[j]);
  *(float4*)(out + ob) = make_float4(o[0], o[1], o[2], o[3]);
  *(float4*)(out + ob + 4) = make_float4(o[4], o[5], o[6], o[7]);
}

// Deferred: out[tok] = sum_{s<=ls} wfull[s][tok] * H_{s+1}[slotmap[s][tok]]
__global__ __launch_bounds__(256) void act_out_final_kernel(
    const u16* __restrict__ h1, const u16* __restrict__ h2,
    const u16* __restrict__ h3, const u16* __restrict__ h4,
    const float* __restrict__ wfull, const int* __restrict__ slotmap,
    const int* __restrict__ last_step, float* __restrict__ out, int M) {
  size_t gid = (size_t)blockIdx.x * 256 + threadIdx.x;
  int tok = (int)(gid >> 7);
  int off = ((int)gid & 127) * 8;
  const int ls = last_step[tok];
  float o[8];
#pragma unroll
  for (int j = 0; j < 8; ++j) o[j] = 0.0f;
  for (int s = 0; s <= ls; ++s) {
    int slot = slotmap[(size_t)s * M + tok];
    float w = wfull[(size_t)s * M + tok];
    const u16* b = (s == 0) ? h1 : (s == 1) ? h2 : (s == 2) ? h3 : h4;
    short8 hv = *(const short8*)(b + (size_t)slot * D_DIM + off);
#pragma unroll
    for (int j = 0; j < 8; ++j) o[j] += w * bf2f((u16)hv[j]);
  }
  size_t ob = (size_t)tok * D_DIM + off;
  *(float4*)(out + ob) = make_float4(o[0], o[1], o[2], o[3]);
  *(float4*)(out + ob + 4) = make_float4(o[4], o[5], o[6], o[7]);
}

__global__ __launch_bounds__(256) void ponder_reduce_kernel(
    const float* __restrict__ pond, float* __restrict__ o, int n) {
  __shared__ float sh[256];
  float a = 0.0f;
  for (int i = threadIdx.x; i < n; i += 256) a += pond[i];
  sh[threadIdx.x] = a;
  __syncthreads();
  for (int s = 128; s; s >>= 1) {
    if ((int)threadIdx.x < s) sh[threadIdx.x] += sh[threadIdx.x + s];
    __syncthreads();
  }
  if (threadIdx.x == 0) o[0] = sh[0] / (float)n;
}

extern "C" void kernel_launch(void* const* d_in, const int* in_sizes, int n_in,
                              void* d_out, int out_size, void* d_ws,
                              size_t ws_size, hipStream_t stream) {
  const float* x = (const float*)d_in[0];
  const float* layer_w = (const float*)d_in[1];
  const float* layer_b = (const float*)d_in[2];
  const float* halt_w = (const float*)d_in[3];
  const float* halt_b = (const float*)d_in[4];
  float* out = (float*)d_out;

  const int D = D_DIM;
  const int M = in_sizes[0] / D;        // 16384
  const int L = in_sizes[1] / (D * D);  // 4
  const size_t MD = (size_t)M * D, DD = (size_t)D * D;

  char* ws = (char*)d_ws;
  size_t off = 0;
  auto alloc = [&](size_t bytes) {
    void* p = ws + off;
    off += (bytes + 255) & ~(size_t)255;
    return p;
  };
  u16* Wth = (u16*)alloc((size_t)L * DD * sizeof(u16));  // bf16 W^T
  float* zpart = (float*)alloc(8 * (size_t)M * 4);
  float* wbuf = (float*)alloc((size_t)M * 4);
  float* wfull = (float*)alloc((size_t)L * M * 4);
  int* slotmap = (int*)alloc((size_t)L * M * 4);
  int* last_step = (int*)alloc((size_t)M * 4);
  float* cum = (float*)alloc((size_t)M * 4);
  float* rem = (float*)alloc((size_t)M * 4);
  float* pond = (float*)alloc((size_t)M * 4);
  int* counts = (int*)alloc(16 * sizeof(int));  // [2s]=exact, [2s+1]=pad
  int* idxA = (int*)alloc((size_t)M * 4);
  int* idxB = (int*)alloc((size_t)M * 4);
  int* srcb = (int*)alloc((size_t)M * 4);

  // hi planes only. xpair: slot0 = xh (later A3), slot1 = A4.
  u16* xpair = (u16*)alloc(2 * MD * sizeof(u16));
  const bool deferred = (off + 2 * MD * sizeof(u16) + 4096) <= ws_size;
  u16 *arch = nullptr, *P1 = nullptr;
  if (deferred) {
    arch = (u16*)alloc(2 * MD * sizeof(u16));  // A1 | A2
  } else {
    P1 = (u16*)alloc(MD * sizeof(u16));
  }
  u16* A[5] = {nullptr, arch, arch ? arch + MD : nullptr, xpair, xpair + MD};

  hipFuncSetAttribute((const void*)gemm_act_kernel,
                      hipFuncAttributeMaxDynamicSharedMemorySize, 32768);

  prep_kernel<<<(unsigned)(1024 + MD / 1024), 256, 0, stream>>>(
      layer_w, Wth, x, xpair, counts, M);

  for (int s = 0; s < L; ++s) {
    const int* idxs = (s == 0) ? nullptr : ((s & 1) ? idxB : idxA);
    const u16* Ahp;
    u16* Hh;
    if (deferred) {
      Ahp = (s == 0) ? xpair : A[s];
      Hh = A[s + 1];
    } else {
      Ahp = (s & 1) ? P1 : xpair;
      Hh = (s & 1) ? xpair : P1;
    }
    gemm_act_kernel<<<dim3((M / 128) * (D / 128)), 256, 32768, stream>>>(
        Ahp, Wth + (size_t)s * DD, layer_b + (size_t)s * D, halt_w, Hh, zpart,
        (s == 0) ? nullptr : srcb, counts + 2 * s + 1, M);
    act_weights_kernel<<<M / 256, 256, 0, stream>>>(
        zpart, halt_b, cum, rem, pond, wbuf, wfull, slotmap, last_step, idxs,
        counts + 2 * s, s, (s == L - 1) ? 1 : 0, M);
    if (!deferred)
      act_out_kernel<<<(unsigned)(MD / 2048), 256, 0, stream>>>(
          Hh, wbuf, idxs, counts + 2 * s, (s > 0) ? 1 : 0, out);
    if (s + 1 < L) {
      int* idxn = ((s + 1) & 1) ? idxB : idxA;
      compact_kernel<<<1, 1024, 0, stream>>>(rem, idxs, counts + 2 * s, idxn,
                                             srcb, counts + 2 * (s + 1));
    }
  }
  if (deferred)
    act_out_final_kernel<<<(unsigned)(MD / 2048), 256, 0, stream>>>(
        A[1], A[2], A[3], A[4], wfull, slotmap, last_step, out, M);
  ponder_reduce_kernel<<<1, 256, 0, stream>>>(pond, out + MD, M);
}

// Round 19
// 304.619 us; speedup vs baseline: 3.0605x; 1.0002x over previous
//
#include <hip/hip_runtime.h>

typedef __attribute__((ext_vector_type(8))) short short8;
typedef __attribute__((ext_vector_type(4))) float f32x4;
typedef __attribute__((ext_vector_type(4))) unsigned short u16x4;
typedef unsigned short u16;

#define D_DIM 1024
#define NKT 32  // K / 32

__device__ __forceinline__ u16 f2bf(float f) {
  unsigned u = __builtin_bit_cast(unsigned, f);
  u += 0x7fffu + ((u >> 16) & 1u);
  return (u16)(u >> 16);
}
__device__ __forceinline__ float bf2f(u16 b) {
  return __builtin_bit_cast(float, ((unsigned)b) << 16);
}
__device__ __forceinline__ float gelu_f(float x) {
  float i = 0.7978845608028654f * (x + 0.044715f * x * x * x);
  float ex = __builtin_amdgcn_exp2f(i * 2.885390081777927f);  // e^{2i}
  float th = 1.0f - 2.0f * __builtin_amdgcn_rcpf(ex + 1.0f);
  return 0.5f * x * (1.0f + th);
}
__device__ __forceinline__ f32x4 mfma16(short8 a, short8 b, f32x4 c) {
  return __builtin_amdgcn_mfma_f32_16x16x32_bf16(a, b, c, 0, 0, 0);
}
__device__ __forceinline__ void glds16(const u16* g, const u16* l) {
  __builtin_amdgcn_global_load_lds(
      (const __attribute__((address_space(1))) void*)g,
      (__attribute__((address_space(3))) void*)l, 16, 0, 0);
}

// ---------------- fused prep: W transpose+bf16 round (blocks 0..1023) and
// x bf16 round (blocks 1024..) ----------------
__global__ __launch_bounds__(256) void prep_kernel(
    const float* __restrict__ W, u16* __restrict__ Wth,
    const float* __restrict__ x, u16* __restrict__ xh, int* __restrict__ counts,
    int M) {
  __shared__ float tile[64][65];
  const int bid = blockIdx.x;
  const int t = threadIdx.x;
  if (bid < 1024) {
    const int k0 = (bid & 15) * 64, n0 = ((bid >> 4) & 15) * 64;
    const size_t lbase = (size_t)(bid >> 8) * D_DIM * D_DIM;
#pragma unroll
    for (int j = 0; j < 16; ++j) {
      int idx = t + 256 * j;
      int r = idx >> 6, c = idx & 63;
      tile[r][c] = W[lbase + (size_t)(k0 + r) * D_DIM + (n0 + c)];
    }
    __syncthreads();
#pragma unroll
    for (int j = 0; j < 16; ++j) {
      int idx = t + 256 * j;
      int r = idx >> 6, c = idx & 63;
      Wth[lbase + (size_t)(n0 + r) * D_DIM + (k0 + c)] = f2bf(tile[c][r]);
    }
  } else {
    if (bid == 1024 && t == 0) {
      counts[0] = M;  // exact count, layer 0
      counts[1] = M;  // padded count, layer 0
    }
    size_t i = ((size_t)(bid - 1024) * 256 + t) * 4;
    const float4 v = *(const float4*)(x + i);
    const float fv[4] = {v.x, v.y, v.z, v.w};
    u16x4 h4;
#pragma unroll
    for (int c = 0; c < 4; ++c) h4[c] = f2bf(fv[c]);
    *(u16x4*)(xh + i) = h4;
  }
}

// ---------------- 128x128 gather-GEMM (pure bf16) + ACT epilogue ----------
// Triple-buffered LDS (3 x 8192 u16 = 48 KB -> 3 blocks/CU), prefetch depth 2,
// counted gate vmcnt(4): tile kt's 4 glds were issued TWO tiles (~2600 cyc)
// before the wait, so the gate never stalls on load latency; kt+1's 4 stay
// in flight across the barrier (m201/AITER discipline). Buffer written by
// stage(kt+2) was last read two barriers ago. 16B slot s of row r holds
// k-chunk s ^ ((r>>1)&3). XCD map mt=(bid&7)+8*(bid>>6); early-exit on
// padded active count.
__global__ __launch_bounds__(256, 3) void gemm_act_kernel(
    const u16* __restrict__ Ahp, const u16* __restrict__ Bhp,
    const float* __restrict__ bias, const float* __restrict__ halt_w,
    u16* __restrict__ Hh, float* __restrict__ zpart,
    const int* __restrict__ srcmap, const int* __restrict__ npadp, int M) {
  extern __shared__ u16 lds[];  // 3 x 8192 u16 = 48 KB
  const int bid = blockIdx.x;   // 1024 blocks
  const int mt = (bid & 7) + 8 * (bid >> 6);
  const int bm0 = mt * 128;
  if (bm0 >= *npadp) return;
  const int bn0 = ((bid >> 3) & 7) * 128;
  const int t = threadIdx.x;
  const int lane = t & 63, wid = t >> 6;
  const int wr = wid >> 1, wc = wid & 1;
  const int g = lane >> 4, r16 = lane & 15;

  const int lrow = lane >> 2;
  const int lchunk = (lane & 3) ^ ((lane >> 3) & 3);
  const int u0 = 2 * wid;
  int ar0 = bm0 + 16 * u0 + lrow, ar1 = ar0 + 16;
  if (srcmap) {
    ar0 = srcmap[ar0];
    ar1 = srcmap[ar1];
  }
  const int br0 = bn0 + 16 * u0 + lrow, br1 = br0 + 16;
  const u16* aSh0 = Ahp + (size_t)ar0 * D_DIM + lchunk * 8;
  const u16* aSh1 = Ahp + (size_t)ar1 * D_DIM + lchunk * 8;
  const u16* bSh0 = Bhp + (size_t)br0 * D_DIM + lchunk * 8;
  const u16* bSh1 = Bhp + (size_t)br1 * D_DIM + lchunk * 8;
  const int dst0 = u0 * 512 + lane * 8, dst1 = dst0 + 512;

  const int fsw = ((g ^ (r16 >> 1)) & 3) * 8;
  int a_rd[4], b_rd[4];
#pragma unroll
  for (int i = 0; i < 4; ++i) {
    a_rd[i] = (wr * 64 + i * 16 + r16) * 32 + fsw;
    b_rd[i] = 4096 + (wc * 64 + i * 16 + r16) * 32 + fsw;
  }

  f32x4 acc[4][4];
#pragma unroll
  for (int i = 0; i < 4; ++i)
#pragma unroll
    for (int j = 0; j < 4; ++j) acc[i][j] = (f32x4)0.0f;

  auto stage = [&](int kt, int buf) {
    const int k0 = kt << 5;
    u16* db = lds + buf * 8192;
    glds16(aSh0 + k0, db + dst0);
    glds16(aSh1 + k0, db + dst1);
    glds16(bSh0 + k0, db + 4096 + dst0);
    glds16(bSh1 + k0, db + 4096 + dst1);
  };
  stage(0, 0);
  stage(1, 1);

  int bufc = 0, bufn = 2;  // buffer of tile kt; buffer for tile kt+2
#pragma unroll 1
  for (int kt = 0; kt < NKT; ++kt) {
    if (kt + 1 < NKT) {
      asm volatile("s_waitcnt vmcnt(4)" ::: "memory");  // kt landed; kt+1 in flight
    } else {
      asm volatile("s_waitcnt vmcnt(0)" ::: "memory");
    }
    __builtin_amdgcn_s_barrier();
    asm volatile("" ::: "memory");
    if (kt + 2 < NKT) stage(kt + 2, bufn);
    const u16* Lb = lds + bufc * 8192;
    short8 ah[4], bh[4];
#pragma unroll
    for (int i = 0; i < 4; ++i) {
      ah[i] = *(const short8*)(Lb + a_rd[i]);
      bh[i] = *(const short8*)(Lb + b_rd[i]);
    }
    __builtin_amdgcn_s_setprio(1);
#pragma unroll
    for (int i = 0; i < 4; ++i)
#pragma unroll
      for (int n = 0; n < 4; ++n) acc[i][n] = mfma16(ah[i], bh[n], acc[i][n]);
    __builtin_amdgcn_s_setprio(0);
    bufc = (bufc == 2) ? 0 : bufc + 1;
    bufn = (bufn == 2) ? 0 : bufn + 1;
  }

  __syncthreads();

  float bv[4], hwv[4];
#pragma unroll
  for (int ni = 0; ni < 4; ++ni) {
    int col = bn0 + wc * 64 + ni * 16 + r16;
    bv[ni] = bias[col];
    hwv[ni] = halt_w[col];
  }
  float zp[4][4];
#pragma unroll
  for (int mi = 0; mi < 4; ++mi)
#pragma unroll
    for (int j = 0; j < 4; ++j) {
      float zz = 0.0f;
#pragma unroll
      for (int ni = 0; ni < 4; ++ni) {
        float v = gelu_f(acc[mi][ni][j] + bv[ni]);
        acc[mi][ni][j] = v;
        zz += v * hwv[ni];
      }
      zp[mi][j] = zz;
    }
#pragma unroll
  for (int off = 1; off < 16; off <<= 1)
#pragma unroll
    for (int mi = 0; mi < 4; ++mi)
#pragma unroll
      for (int j = 0; j < 4; ++j) zp[mi][j] += __shfl_xor(zp[mi][j], off);
  float* zf = (float*)lds;  // [2][128]
  if (r16 == 0) {
#pragma unroll
    for (int mi = 0; mi < 4; ++mi)
#pragma unroll
      for (int j = 0; j < 4; ++j)
        zf[wc * 128 + wr * 64 + mi * 16 + g * 4 + j] = zp[mi][j];
  }
  __syncthreads();
  if (t < 128) zpart[(size_t)(bn0 >> 7) * M + bm0 + t] = zf[t] + zf[128 + t];
  __syncthreads();

  u16* hp = lds;  // [128][128] u16 = 32 KB (< 48 KB declared)
#pragma unroll
  for (int mi = 0; mi < 4; ++mi)
#pragma unroll
    for (int ni = 0; ni < 4; ++ni)
#pragma unroll
      for (int j = 0; j < 4; ++j)
        hp[(wr * 64 + mi * 16 + g * 4 + j) * 128 + wc * 64 + ni * 16 + r16] =
            f2bf(acc[mi][ni][j]);
  __syncthreads();
#pragma unroll
  for (int p = 0; p < 8; ++p) {
    int idx = p * 256 + t;
    int r = idx >> 4, c = idx & 15;
    *(short8*)(Hh + (size_t)(bm0 + r) * D_DIM + bn0 + c * 8) =
        *(const short8*)&hp[r * 128 + c * 8];
  }
}

// ---------------- ACT scalar kernels (round-13 structure) ----------------
__global__ __launch_bounds__(256) void act_weights_kernel(
    const float* __restrict__ zpart, const float* __restrict__ halt_b,
    float* __restrict__ cum, float* __restrict__ rem, float* __restrict__ pond,
    float* __restrict__ wout, float* __restrict__ wfull,
    int* __restrict__ slotmap, int* __restrict__ last_step,
    const int* __restrict__ idx, const int* __restrict__ np, int step,
    int last, int M) {
  int slot = blockIdx.x * 256 + threadIdx.x;
  if (slot >= *np) return;
  int tok = idx ? idx[slot] : slot;
  float z = halt_b[0];
#pragma unroll
  for (int nb = 0; nb < 8; ++nb) z += zpart[(size_t)nb * M + slot];
  float p = 1.0f / (1.0f + expf(-z));
  float c, r, q;
  if (step == 0) {
    c = 0.0f; r = 1.0f; q = 0.0f;
  } else {
    c = cum[tok]; r = rem[tok]; q = pond[tok];
  }
  float weight = last ? r : (((c + p) >= 0.99f) ? r : p);
  q += weight;
  c += weight;
  r = fmaxf(1.0f - c, 0.0f);
  cum[tok] = c;
  rem[tok] = r;
  pond[tok] = q;
  wout[slot] = weight;
  wfull[(size_t)step * M + tok] = weight;
  slotmap[(size_t)step * M + tok] = slot;
  last_step[tok] = step;
}

__global__ __launch_bounds__(1024) void compact_kernel(
    const float* __restrict__ rem, const int* __restrict__ idx_cur,
    const int* __restrict__ ncur_p, int* __restrict__ idx_next,
    int* __restrict__ src_next, int* __restrict__ cnt_next) {
  __shared__ int sc[1024];
  const int t = threadIdx.x;
  const int n = *ncur_p;
  const int base = t * 16;
  int lc = 0;
#pragma unroll
  for (int i = 0; i < 16; ++i) {
    int j = base + i;
    if (j < n) {
      int tok = idx_cur ? idx_cur[j] : j;
      if (rem[tok] > 0.0f) ++lc;
    }
  }
  sc[t] = lc;
  __syncthreads();
  for (int d = 1; d < 1024; d <<= 1) {
    int v = (t >= d) ? sc[t - d] : 0;
    __syncthreads();
    sc[t] += v;
    __syncthreads();
  }
  int pos = sc[t] - lc;
  const int total = sc[1023];
#pragma unroll
  for (int i = 0; i < 16; ++i) {
    int j = base + i;
    if (j < n) {
      int tok = idx_cur ? idx_cur[j] : j;
      if (rem[tok] > 0.0f) {
        idx_next[pos] = tok;
        src_next[pos] = j;
        ++pos;
      }
    }
  }
  if (t == 0) {
    int pad = (total + 127) & ~127;
    cnt_next[0] = total;
    cnt_next[1] = pad;
    for (int j = total; j < pad; ++j) {
      idx_next[j] = -1;
      src_next[j] = 0;
    }
  }
}

// Fallback per-step: out[tok] (+)= w[slot] * h[slot]
__global__ __launch_bounds__(256) void act_out_kernel(
    const u16* __restrict__ h, const float* __restrict__ w,
    const int* __restrict__ idx, const int* __restrict__ np, int accum,
    float* __restrict__ out) {
  size_t gid = (size_t)blockIdx.x * 256 + threadIdx.x;
  int slot = (int)(gid >> 7);
  if (slot >= *np) return;
  int off = ((int)gid & 127) * 8;
  int tok = idx ? idx[slot] : slot;
  size_t hb = (size_t)slot * D_DIM + off;
  size_t ob = (size_t)tok * D_DIM + off;
  float ws = w[slot];
  short8 hi = *(const short8*)(h + hb);
  float o[8];
  if (accum) {
    float4 a = *(const float4*)(out + ob);
    float4 b = *(const float4*)(out + ob + 4);
    o[0] = a.x; o[1] = a.y; o[2] = a.z; o[3] = a.w;
    o[4] = b.x; o[5] = b.y; o[6] = b.z; o[7] = b.w;
  } else {
#pragma unroll
    for (int j = 0; j < 8; ++j) o[j] = 0.0f;
  }
#pragma unroll
  for (int j = 0; j < 8; ++j) o[j] += ws * bf2f((u16)hi[j]);
  *(float4*)(out + ob) = make_float4(o[0], o[1], o[2], o[3]);
  *(float4*)(out + ob + 4) = make_float4(o[4], o[5], o[6], o[7]);
}

// Deferred: out[tok] = sum_{s<=ls} wfull[s][tok] * H_{s+1}[slotmap[s][tok]]
__global__ __launch_bounds__(256) void act_out_final_kernel(
    const u16* __restrict__ h1, const u16* __restrict__ h2,
    const u16* __restrict__ h3, const u16* __restrict__ h4,
    const float* __restrict__ wfull, const int* __restrict__ slotmap,
    const int* __restrict__ last_step, float* __restrict__ out, int M) {
  size_t gid = (size_t)blockIdx.x * 256 + threadIdx.x;
  int tok = (int)(gid >> 7);
  int off = ((int)gid & 127) * 8;
  const int ls = last_step[tok];
  float o[8];
#pragma unroll
  for (int j = 0; j < 8; ++j) o[j] = 0.0f;
  for (int s = 0; s <= ls; ++s) {
    int slot = slotmap[(size_t)s * M + tok];
    float w = wfull[(size_t)s * M + tok];
    const u16* b = (s == 0) ? h1 : (s == 1) ? h2 : (s == 2) ? h3 : h4;
    short8 hv = *(const short8*)(b + (size_t)slot * D_DIM + off);
#pragma unroll
    for (int j = 0; j < 8; ++j) o[j] += w * bf2f((u16)hv[j]);
  }
  size_t ob = (size_t)tok * D_DIM + off;
  *(float4*)(out + ob) = make_float4(o[0], o[1], o[2], o[3]);
  *(float4*)(out + ob + 4) = make_float4(o[4], o[5], o[6], o[7]);
}

__global__ __launch_bounds__(256) void ponder_reduce_kernel(
    const float* __restrict__ pond, float* __restrict__ o, int n) {
  __shared__ float sh[256];
  float a = 0.0f;
  for (int i = threadIdx.x; i < n; i += 256) a += pond[i];
  sh[threadIdx.x] = a;
  __syncthreads();
  for (int s = 128; s; s >>= 1) {
    if ((int)threadIdx.x < s) sh[threadIdx.x] += sh[threadIdx.x + s];
    __syncthreads();
  }
  if (threadIdx.x == 0) o[0] = sh[0] / (float)n;
}

extern "C" void kernel_launch(void* const* d_in, const int* in_sizes, int n_in,
                              void* d_out, int out_size, void* d_ws,
                              size_t ws_size, hipStream_t stream) {
  const float* x = (const float*)d_in[0];
  const float* layer_w = (const float*)d_in[1];
  const float* layer_b = (const float*)d_in[2];
  const float* halt_w = (const float*)d_in[3];
  const float* halt_b = (const float*)d_in[4];
  float* out = (float*)d_out;

  const int D = D_DIM;
  const int M = in_sizes[0] / D;        // 16384
  const int L = in_sizes[1] / (D * D);  // 4
  const size_t MD = (size_t)M * D, DD = (size_t)D * D;

  char* ws = (char*)d_ws;
  size_t off = 0;
  auto alloc = [&](size_t bytes) {
    void* p = ws + off;
    off += (bytes + 255) & ~(size_t)255;
    return p;
  };
  u16* Wth = (u16*)alloc((size_t)L * DD * sizeof(u16));  // bf16 W^T
  float* zpart = (float*)alloc(8 * (size_t)M * 4);
  float* wbuf = (float*)alloc((size_t)M * 4);
  float* wfull = (float*)alloc((size_t)L * M * 4);
  int* slotmap = (int*)alloc((size_t)L * M * 4);
  int* last_step = (int*)alloc((size_t)M * 4);
  float* cum = (float*)alloc((size_t)M * 4);
  float* rem = (float*)alloc((size_t)M * 4);
  float* pond = (float*)alloc((size_t)M * 4);
  int* counts = (int*)alloc(16 * sizeof(int));  // [2s]=exact, [2s+1]=pad
  int* idxA = (int*)alloc((size_t)M * 4);
  int* idxB = (int*)alloc((size_t)M * 4);
  int* srcb = (int*)alloc((size_t)M * 4);

  // hi planes only. xpair: slot0 = xh (later A3), slot1 = A4.
  u16* xpair = (u16*)alloc(2 * MD * sizeof(u16));
  const bool deferred = (off + 2 * MD * sizeof(u16) + 4096) <= ws_size;
  u16 *arch = nullptr, *P1 = nullptr;
  if (deferred) {
    arch = (u16*)alloc(2 * MD * sizeof(u16));  // A1 | A2
  } else {
    P1 = (u16*)alloc(MD * sizeof(u16));
  }
  u16* A[5] = {nullptr, arch, arch ? arch + MD : nullptr, xpair, xpair + MD};

  hipFuncSetAttribute((const void*)gemm_act_kernel,
                      hipFuncAttributeMaxDynamicSharedMemorySize, 49152);

  prep_kernel<<<(unsigned)(1024 + MD / 1024), 256, 0, stream>>>(
      layer_w, Wth, x, xpair, counts, M);

  for (int s = 0; s < L; ++s) {
    const int* idxs = (s == 0) ? nullptr : ((s & 1) ? idxB : idxA);
    const u16* Ahp;
    u16* Hh;
    if (deferred) {
      Ahp = (s == 0) ? xpair : A[s];
      Hh = A[s + 1];
    } else {
      Ahp = (s & 1) ? P1 : xpair;
      Hh = (s & 1) ? xpair : P1;
    }
    gemm_act_kernel<<<dim3((M / 128) * (D / 128)), 256, 49152, stream>>>(
        Ahp, Wth + (size_t)s * DD, layer_b + (size_t)s * D, halt_w, Hh, zpart,
        (s == 0) ? nullptr : srcb, counts + 2 * s + 1, M);
    act_weights_kernel<<<M / 256, 256, 0, stream>>>(
        zpart, halt_b, cum, rem, pond, wbuf, wfull, slotmap, last_step, idxs,
        counts + 2 * s, s, (s == L - 1) ? 1 : 0, M);
    if (!deferred)
      act_out_kernel<<<(unsigned)(MD / 2048), 256, 0, stream>>>(
          Hh, wbuf, idxs, counts + 2 * s, (s > 0) ? 1 : 0, out);
    if (s + 1 < L) {
      int* idxn = ((s + 1) & 1) ? idxB : idxA;
      compact_kernel<<<1, 1024, 0, stream>>>(rem, idxs, counts + 2 * s, idxn,
                                             srcb, counts + 2 * (s + 1));
    }
  }
  if (deferred)
    act_out_final_kernel<<<(unsigned)(MD / 2048), 256, 0, stream>>>(
        A[1], A[2], A[3], A[4], wfull, slotmap, last_step, out, M);
  ponder_reduce_kernel<<<1, 256, 0, stream>>>(pond, out + MD, M);
}